// Round 1
// baseline (754.268 us; speedup 1.0000x reference)
//
#include <hip/hip_runtime.h>
#include <stdint.h>

// Attention_48945447306134 on MI355X.
//   GEMM1: QKV = xb @ [wq*C|wk|wv]^T  (wq pre-scaled by softmax_scale*log2e)
//   RoPE in place; V pre-transposed to Vt[b][hk][d][s]
//   Flash attention, TRANSPOSED algebra: S^T = K Q^T, O^T = V^T P^T
//   This rev: T14 async reg-prefetch of K/V tiles (raw s_barrier, no vmcnt
//   drain mid-loop), T13 defer-max (THR=8 in log2 units), v_cvt_pk_bf16_f32
//   packing, tree max/sum reductions, setprio around MFMA clusters.
//   GEMM2: out = attn @ woT (fp32 out)

typedef unsigned short u16;
typedef __bf16 bf16x8 __attribute__((ext_vector_type(8)));
typedef float  f32x4  __attribute__((ext_vector_type(4)));

#define GLOAD16(gp, lp)                                                        \
  __builtin_amdgcn_global_load_lds(                                            \
      (const __attribute__((address_space(1))) void*)(gp),                     \
      (__attribute__((address_space(3))) void*)(lp), 16, 0, 0)

__device__ __forceinline__ u16 f2b(float f) {  // RNE f32->bf16
  union { float f; uint32_t u; } v; v.f = f;
  uint32_t r = v.u + 0x7FFFu + ((v.u >> 16) & 1u);
  return (u16)(r >> 16);
}
__device__ __forceinline__ float b2f(u16 h) {
  union { uint32_t u; float f; } v; v.u = ((uint32_t)h) << 16;
  return v.f;
}
// RNE pack via HW instruction: 2 instrs instead of ~10 VALU ops
__device__ __forceinline__ uint2 pack4(float a, float b, float c, float d) {
  uint2 r;
  asm("v_cvt_pk_bf16_f32 %0, %1, %2" : "=v"(r.x) : "v"(a), "v"(b));
  asm("v_cvt_pk_bf16_f32 %0, %1, %2" : "=v"(r.y) : "v"(c), "v"(d));
  return r;
}

// block barrier that does NOT drain vmcnt (keeps reg-prefetch loads in
// flight). lgkmcnt(0) first = my LDS ops complete; barrier = everyone's are;
// trailing empty asm = compiler reordering fence for memory ops.
__device__ __forceinline__ void bar_sync() {
  asm volatile("s_waitcnt lgkmcnt(0)" ::: "memory");
  __builtin_amdgcn_s_barrier();
  asm volatile("" ::: "memory");
}

// ---------------- cast x -> bf16 ----------------
__global__ __launch_bounds__(256) void cast_x_kernel(const float4* __restrict__ in,
                                                     ushort4* __restrict__ out) {
  int i = blockIdx.x * 256 + threadIdx.x;
  float4 v = in[i];
  ushort4 o;
  o.x = f2b(v.x); o.y = f2b(v.y); o.z = f2b(v.z); o.w = f2b(v.w);
  out[i] = o;
}

// ------------- cast + transpose weight: W (KxN f32) -> WT (NxK bf16), * scale -------------
__global__ __launch_bounds__(256) void wtrans_kernel(const float* __restrict__ W,
                                                     u16* __restrict__ WT,
                                                     int K, int N, float scale) {
  __shared__ float t[32][33];
  int n0 = blockIdx.x * 32, k0 = blockIdx.y * 32;
  int tx = threadIdx.x, ty = threadIdx.y;  // 32 x 8
  for (int r = 0; r < 4; r++)
    t[ty + r * 8][tx] = W[(size_t)(k0 + ty + r * 8) * N + n0 + tx];
  __syncthreads();
  for (int r = 0; r < 4; r++)
    WT[(size_t)(n0 + ty + r * 8) * K + k0 + tx] = f2b(t[tx][ty + r * 8] * scale);
}

// ---------------- GEMM: C(MxN) = A(MxK) * BT(NxK)^T, m97 structure ----------------
template <bool BF16OUT>
__global__ __launch_bounds__(256) void gemm_bt_kernel(const u16* __restrict__ A,
                                                      const u16* __restrict__ BT,
                                                      void* __restrict__ Cv,
                                                      int K, int N) {
  __shared__ u16 As[128 * 32];
  __shared__ u16 Bs[128 * 32];
  const int tid = threadIdx.x;
  const int wave = tid >> 6, lane = tid & 63;
  const int quad = lane >> 4, l16 = lane & 15;
  const int wm = (wave >> 1) * 64, wn = (wave & 1) * 64;
  const size_t m0 = (size_t)blockIdx.y * 128, n0 = (size_t)blockIdx.x * 128;

  f32x4 acc[4][4] = {};
  const int srow = lane >> 2;
  const int scol = (lane & 3) * 8;
  const u16* Ag = A + (m0 + wave * 16 + srow) * (size_t)K + scol;
  const u16* Bg = BT + (n0 + wave * 16 + srow) * (size_t)K + scol;

  for (int k0 = 0; k0 < K; k0 += 32) {
    for (int rd = 0; rd < 2; rd++) {
      GLOAD16(Ag + (size_t)rd * 64 * K + k0, &As[(rd * 64 + wave * 16) * 32]);
      GLOAD16(Bg + (size_t)rd * 64 * K + k0, &Bs[(rd * 64 + wave * 16) * 32]);
    }
    __syncthreads();
    bf16x8 af[4], bf[4];
    for (int i = 0; i < 4; i++)
      af[i] = *(const bf16x8*)&As[(wm + i * 16 + l16) * 32 + quad * 8];
    for (int i = 0; i < 4; i++)
      bf[i] = *(const bf16x8*)&Bs[(wn + i * 16 + l16) * 32 + quad * 8];
    for (int mi = 0; mi < 4; mi++)
      for (int ni = 0; ni < 4; ni++)
        acc[mi][ni] = __builtin_amdgcn_mfma_f32_16x16x32_bf16(af[mi], bf[ni], acc[mi][ni], 0, 0, 0);
    __syncthreads();
  }
  for (int mi = 0; mi < 4; mi++)
    for (int ni = 0; ni < 4; ni++)
      for (int r = 0; r < 4; r++) {
        size_t row = m0 + wm + mi * 16 + quad * 4 + r;
        size_t col = n0 + wn + ni * 16 + l16;
        if (BF16OUT) ((u16*)Cv)[row * N + col] = f2b(acc[mi][ni][r]);
        else         ((float*)Cv)[row * N + col] = acc[mi][ni][r];
      }
}

// ---------------- RoPE in place on QKV cols [0,2560) ----------------
__global__ __launch_bounds__(256) void rope_kernel(u16* __restrict__ QKV,
                                                   const float* __restrict__ cs,
                                                   const float* __restrict__ sn) {
  int tid = blockIdx.x * 256 + threadIdx.x;
  int row = tid / 1280;
  int p = tid - row * 1280;
  int s = row & 2047;
  int head = p >> 6, i = p & 63;
  u16* ptr = QKV + (size_t)row * 3072 + head * 128 + i * 2;
  unsigned int v = *(unsigned int*)ptr;
  float x0 = b2f((u16)(v & 0xffff)), x1 = b2f((u16)(v >> 16));
  float c = cs[s * 64 + i], ss = sn[s * 64 + i];
  u16 o0 = f2b(x0 * c - x1 * ss);
  u16 o1 = f2b(x0 * ss + x1 * c);
  *(unsigned int*)ptr = (unsigned int)o0 | ((unsigned int)o1 << 16);
}

// ---------------- V transpose ----------------
__global__ __launch_bounds__(256) void vtrans_kernel(const u16* __restrict__ QKV,
                                                     u16* __restrict__ Vt) {
  __shared__ u16 t[32][33];
  int b = blockIdx.z >> 2, hk = blockIdx.z & 3;
  int s0 = blockIdx.x * 32, d0 = blockIdx.y * 32;
  int tx = threadIdx.x, ty = threadIdx.y;
  const u16* src = QKV + (size_t)(b * 2048 + s0) * 3072 + 2560 + hk * 128 + d0;
  for (int r = 0; r < 4; r++)
    t[ty + r * 8][tx] = src[(size_t)(ty + r * 8) * 3072 + tx];
  __syncthreads();
  u16* dst = Vt + ((size_t)((b * 4 + hk) * 128 + d0)) * 2048 + s0;
  for (int r = 0; r < 4; r++)
    dst[(size_t)(ty + r * 8) * 2048 + tx] = t[tx][ty + r * 8];
}

// ---------------- flash attention (transposed algebra) ----------------
// grid (qt=16, h=16, b=4), 256 threads = 4 waves, 32 q-rows/wave.
// S^T = K.Q^T: C-layout col(l16)=q, row(quad*4+r)=key -> per-q softmax needs
// only xor-16/xor-32 shuffles; P packed b64 into [q][key]; O^T = V^T.P^T puts
// alpha/l on the same lanes that hold O. LDS: KP(32K, K then P) + Vls(32K).
// Tile kt staged by GLOAD16 once (prologue); tiles kt+1 prefetched into
// VGPRs during compute and ds_written after the loop-end barrier.
__global__ __launch_bounds__(256, 2) void attn_kernel(const u16* __restrict__ QKV,
                                                      const u16* __restrict__ Vt,
                                                      u16* __restrict__ AO) {
  __shared__ u16 KP[128 * 128];
  __shared__ u16 Vls[128 * 128];
  const int tid = threadIdx.x;
  const int wave = tid >> 6, lane = tid & 63;
  const int quad = lane >> 4, l16 = lane & 15;
  const int qt = blockIdx.x, h = blockIdx.y, b = blockIdx.z;
  const int hk = h >> 2;
  const int sw = l16 & 7;  // row-dependent swizzle key for this lane's rows

  // Q fragments (B-operand: n=q=l16, k=d)
  bf16x8 qf[2][4];
  {
    const u16* Qb = QKV + (size_t)(b * 2048 + qt * 128 + wave * 32) * 3072 + h * 128;
    for (int qb = 0; qb < 2; qb++)
      for (int ki = 0; ki < 4; ki++)
        qf[qb][ki] = *(const bf16x8*)(Qb + (size_t)(qb * 16 + l16) * 3072 + ki * 32 + quad * 8);
  }
  f32x4 o[8][2] = {};            // O^T: [db][qb], col=q(l16), row=d(quad*4+r)
  float m_[2] = {-1e30f, -1e30f}, l_[2] = {0.f, 0.f};

  const u16* Kg0 = QKV + 2048 + hk * 128;
  const u16* Vg0 = Vt + (size_t)((b * 4 + hk) * 128) * 2048;
  const int r4 = lane >> 4, c16 = lane & 15;

  // ---- prologue: stage tile 0 via global_load_lds (vmcnt drained by syncthreads)
  {
    const u16* Kg = Kg0 + (size_t)(b * 2048) * 3072;
    const u16* Vg = Vg0;
    for (int i = 0; i < 8; i++) {
      int grp = i * 4 + wave;
      int row = grp * 4 + r4;
      int ch = c16 ^ (row & 7);
      GLOAD16(Kg + (size_t)row * 3072 + ch * 8, &KP[grp * 512]);
    }
    for (int i = 0; i < 8; i++) {
      int grp = i * 4 + wave;
      int row = grp * 4 + r4;
      int ch = c16 ^ (row & 7);
      GLOAD16(Vg + (size_t)row * 2048 + ch * 8, &Vls[grp * 512]);
    }
  }
  __syncthreads();

  // ---- per-lane prefetch geometry (identical mapping to the GLOAD16 staging:
  // row = i*16 + wave*4 + r4, ch = c16 ^ (row&7) (i-independent since i*16%8==0),
  // lds dst = grp*512 + lane*8 u16, grp = i*4 + wave)
  const int prow = wave * 4 + r4;
  const int pch = c16 ^ (prow & 7);
  const u16* Kpf = Kg0 + ((size_t)(b * 2048 + 128) + prow) * 3072 + pch * 8;  // tile 1
  const u16* Vpf = Vg0 + (size_t)prow * 2048 + pch * 8 + 128;                 // tile 1
  const int ldsoff = wave * 512 + lane * 8;  // u16 units; + i*2048 per chunk

  for (int kt = 0; kt < 16; kt++) {
    uint4 kreg[8], vreg[8];
    // issue K prefetch for tile kt+1; hides under QK^T + softmax
    if (kt < 15) {
#pragma unroll
      for (int i = 0; i < 8; i++)
        kreg[i] = *(const uint4*)(Kpf + (size_t)i * 49152);  // i*16*3072
    }

    // S^T = K Q^T : A = K-frag (m=key), B = Q-frag (n=q)
    f32x4 s[8][2];
    for (int kb = 0; kb < 8; kb++) {
      bf16x8 kf[4];
      int a0 = (kb * 16 + l16) * 128 + ((quad ^ sw) << 3);
      for (int ki = 0; ki < 4; ki++)
        kf[ki] = *(const bf16x8*)&KP[a0 ^ (ki * 32)];
      __builtin_amdgcn_s_setprio(1);
      for (int qb = 0; qb < 2; qb++) {
        f32x4 a = {0.f, 0.f, 0.f, 0.f};
        for (int ki = 0; ki < 4; ki++)
          a = __builtin_amdgcn_mfma_f32_16x16x32_bf16(kf[ki], qf[qb][ki], a, 0, 0, 0);
        s[kb][qb] = a;
      }
      __builtin_amdgcn_s_setprio(0);
    }

    // online softmax per q (q = qb*16 + l16); scores pre-scaled by C*log2e.
    // tree max (v_max3-friendly) + defer-max: skip O-rescale when no row grew
    // by more than THR=8 (log2 units); P then bounded by 2^8, fine in bf16.
    for (int qb = 0; qb < 2; qb++) {
      float mk[8];
#pragma unroll
      for (int kb = 0; kb < 8; kb++)
        mk[kb] = fmaxf(fmaxf(s[kb][qb][0], s[kb][qb][1]),
                       fmaxf(s[kb][qb][2], s[kb][qb][3]));
      float mx = fmaxf(fmaxf(fmaxf(mk[0], mk[1]), fmaxf(mk[2], mk[3])),
                       fmaxf(fmaxf(mk[4], mk[5]), fmaxf(mk[6], mk[7])));
      mx = fmaxf(mx, __shfl_xor(mx, 16, 64));
      mx = fmaxf(mx, __shfl_xor(mx, 32, 64));
      float mn = m_[qb], al = 1.0f;
      if (!__all(mx <= m_[qb] + 8.0f)) {
        mn = fmaxf(m_[qb], mx);
        al = exp2f(m_[qb] - mn);
        m_[qb] = mn;
#pragma unroll
        for (int db = 0; db < 8; db++) o[db][qb] *= al;
      }
      float rs = 0.f;
#pragma unroll
      for (int kb = 0; kb < 8; kb++) {
        float p0 = exp2f(s[kb][qb][0] - mn), p1 = exp2f(s[kb][qb][1] - mn);
        float p2 = exp2f(s[kb][qb][2] - mn), p3 = exp2f(s[kb][qb][3] - mn);
        s[kb][qb][0] = p0; s[kb][qb][1] = p1;
        s[kb][qb][2] = p2; s[kb][qb][3] = p3;
        rs += (p0 + p1) + (p2 + p3);
      }
      rs += __shfl_xor(rs, 16, 64);
      rs += __shfl_xor(rs, 32, 64);
      l_[qb] = l_[qb] * al + rs;
    }

    bar_sync();  // #2: all waves' K reads done before P overwrites KP (no vmcnt drain)

    // issue V prefetch for tile kt+1; hides under P-write + PV
    if (kt < 15) {
#pragma unroll
      for (int i = 0; i < 8; i++)
        vreg[i] = *(const uint4*)(Vpf + (size_t)i * 32768);  // i*16*2048
    }

    // P -> KP as [q][key], packed b64 (4 contiguous keys per lane)
    for (int qb = 0; qb < 2; qb++) {
      int rq = wave * 32 + qb * 16 + l16;
      for (int kb = 0; kb < 8; kb++) {
        int ch = (kb * 2 + (quad >> 1)) ^ sw;
        uint2 pv = pack4(s[kb][qb][0], s[kb][qb][1], s[kb][qb][2], s[kb][qb][3]);
        *(uint2*)&KP[rq * 128 + (ch << 3) + (quad & 1) * 4] = pv;
      }
    }
    // O^T += V^T P^T : A = V-frag (m=d), B = P-frag (n=q, own rows only)
    bf16x8 pf[2][4];
    for (int qb = 0; qb < 2; qb++) {
      int a0 = (wave * 32 + qb * 16 + l16) * 128 + ((quad ^ sw) << 3);
      for (int ki = 0; ki < 4; ki++)
        pf[qb][ki] = *(const bf16x8*)&KP[a0 ^ (ki * 32)];
    }
    for (int db = 0; db < 8; db++) {
      bf16x8 vf[4];
      int a0 = (db * 16 + l16) * 128 + ((quad ^ sw) << 3);
      for (int ki = 0; ki < 4; ki++)
        vf[ki] = *(const bf16x8*)&Vls[a0 ^ (ki * 32)];
      __builtin_amdgcn_s_setprio(1);
      for (int qb = 0; qb < 2; qb++)
        for (int ki = 0; ki < 4; ki++)
          o[db][qb] = __builtin_amdgcn_mfma_f32_16x16x32_bf16(vf[ki], pf[qb][ki], o[db][qb], 0, 0, 0);
      __builtin_amdgcn_s_setprio(0);
    }

    bar_sync();  // #3: all waves' V+P reads done before restage

    if (kt < 15) {
      // compiler inserts the vmcnt wait for kreg/vreg here (loads long done)
#pragma unroll
      for (int i = 0; i < 8; i++) *(uint4*)&KP[ldsoff + i * 2048] = kreg[i];
#pragma unroll
      for (int i = 0; i < 8; i++) *(uint4*)&Vls[ldsoff + i * 2048] = vreg[i];
      Kpf += 393216;  // 128*3072
      Vpf += 128;
      bar_sync();  // #1': staged tile visible to all waves
    }
  }

  // epilogue: O^T/l -> LDS [q][d] packed b64 -> coalesced global store
  float inv[2] = {1.0f / l_[0], 1.0f / l_[1]};
  for (int qb = 0; qb < 2; qb++) {
    int rq = wave * 32 + qb * 16 + l16;
    for (int db = 0; db < 8; db++) {
      int ch = (db * 2 + (quad >> 1)) ^ sw;
      uint2 pv = pack4(o[db][qb][0] * inv[qb], o[db][qb][1] * inv[qb],
                       o[db][qb][2] * inv[qb], o[db][qb][3] * inv[qb]);
      *(uint2*)&KP[rq * 128 + (ch << 3) + (quad & 1) * 4] = pv;
    }
  }
  __syncthreads();
  u16* Ab = AO + (size_t)(b * 2048 + qt * 128) * 2048 + h * 128;
  for (int i = 0; i < 8; i++) {
    int row = i * 16 + (tid >> 4);
    int seg = tid & 15;
    int pc = seg ^ (row & 7);
    *(uint4*)(Ab + (size_t)row * 2048 + seg * 8) = *(const uint4*)&KP[row * 128 + pc * 8];
  }
}

// ---------------- launch ----------------
extern "C" void kernel_launch(void* const* d_in, const int* in_sizes, int n_in,
                              void* d_out, int out_size, void* d_ws, size_t ws_size,
                              hipStream_t stream) {
  (void)in_sizes; (void)n_in; (void)out_size; (void)ws_size;
  const float* x    = (const float*)d_in[0];
  const float* fcos = (const float*)d_in[1];
  const float* fsin = (const float*)d_in[2];
  const float* wq   = (const float*)d_in[3];
  const float* wk   = (const float*)d_in[4];
  const float* wv   = (const float*)d_in[5];
  const float* wo   = (const float*)d_in[6];

  char* w = (char*)d_ws;
  u16* xb  = (u16*)w;                               // 8192x2048 bf16, reused as attn_out
  u16* wT  = (u16*)(w + 33554432);                  // 3072x2048 bf16
  u16* woT = (u16*)(w + 33554432 + 12582912);       // 2048x2048 bf16
  u16* QKV = (u16*)(w + 33554432 + 12582912 + 8388608);            // 8192x3072 bf16
  u16* Vt  = (u16*)(w + 33554432 + 12582912 + 8388608 + 50331648); // 16x128x2048 bf16
  u16* AO  = xb;

  const float C = 0.08838834764831845f * 1.44269504088896340f;  // 1/sqrt(128)*log2(e)

  cast_x_kernel<<<16384, 256, 0, stream>>>((const float4*)x, (ushort4*)xb);
  wtrans_kernel<<<dim3(64, 64), dim3(32, 8), 0, stream>>>(wq, wT, 2048, 2048, C);
  wtrans_kernel<<<dim3(16, 64), dim3(32, 8), 0, stream>>>(wk, wT + (size_t)2048 * 2048, 2048, 512, 1.0f);
  wtrans_kernel<<<dim3(16, 64), dim3(32, 8), 0, stream>>>(wv, wT + (size_t)2560 * 2048, 2048, 512, 1.0f);
  wtrans_kernel<<<dim3(64, 64), dim3(32, 8), 0, stream>>>(wo, woT, 2048, 2048, 1.0f);

  gemm_bt_kernel<true><<<dim3(24, 64), 256, 0, stream>>>(xb, wT, QKV, 2048, 3072);
  rope_kernel<<<40960, 256, 0, stream>>>(QKV, fcos, fsin);
  vtrans_kernel<<<dim3(64, 4, 16), dim3(32, 8), 0, stream>>>(QKV, Vt);
  attn_kernel<<<dim3(16, 16, 4), 256, 0, stream>>>(QKV, Vt, AO);
  gemm_bt_kernel<false><<<dim3(16, 64), 256, 0, stream>>>(AO, woT, (float*)d_out, 2048, 2048);
}

// Round 2
// 669.064 us; speedup vs baseline: 1.1273x; 1.1273x over previous
//
#include <hip/hip_runtime.h>
#include <stdint.h>

// Attention_48945447306134 on MI355X.
//   GEMM1: QKV = xb @ [wq*C|wk|wv]^T  (wq pre-scaled by softmax_scale*log2e)
//   RoPE in place; V pre-transposed to Vt[b][hk][d][s]
//   Flash attention, TRANSPOSED algebra: S^T = K Q^T, O^T = V^T P^T
//   This rev: K-only reg-prefetch (32 VGPR, no spill); V staged via
//   global_load_lds issued post-barrier#3, drained by counted vmcnt(8) at
//   barrier#2 (overlaps QK+softmax). Keeps: defer-max THR=8, cvt_pk packing,
//   tree reductions, setprio around MFMA clusters.
//   GEMM2: out = attn @ woT (fp32 out)

typedef unsigned short u16;
typedef __bf16 bf16x8 __attribute__((ext_vector_type(8)));
typedef float  f32x4  __attribute__((ext_vector_type(4)));

#define GLOAD16(gp, lp)                                                        \
  __builtin_amdgcn_global_load_lds(                                            \
      (const __attribute__((address_space(1))) void*)(gp),                     \
      (__attribute__((address_space(3))) void*)(lp), 16, 0, 0)

__device__ __forceinline__ u16 f2b(float f) {  // RNE f32->bf16
  union { float f; uint32_t u; } v; v.f = f;
  uint32_t r = v.u + 0x7FFFu + ((v.u >> 16) & 1u);
  return (u16)(r >> 16);
}
__device__ __forceinline__ float b2f(u16 h) {
  union { uint32_t u; float f; } v; v.u = ((uint32_t)h) << 16;
  return v.f;
}
// RNE pack via HW instruction
__device__ __forceinline__ uint2 pack4(float a, float b, float c, float d) {
  uint2 r;
  asm("v_cvt_pk_bf16_f32 %0, %1, %2" : "=v"(r.x) : "v"(a), "v"(b));
  asm("v_cvt_pk_bf16_f32 %0, %1, %2" : "=v"(r.y) : "v"(c), "v"(d));
  return r;
}

// block barrier that does NOT drain vmcnt (keeps prefetch loads in flight).
__device__ __forceinline__ void bar_sync() {
  asm volatile("s_waitcnt lgkmcnt(0)" ::: "memory");
  __builtin_amdgcn_s_barrier();
  asm volatile("" ::: "memory");
}

// ---------------- cast x -> bf16 ----------------
__global__ __launch_bounds__(256) void cast_x_kernel(const float4* __restrict__ in,
                                                     ushort4* __restrict__ out) {
  int i = blockIdx.x * 256 + threadIdx.x;
  float4 v = in[i];
  ushort4 o;
  o.x = f2b(v.x); o.y = f2b(v.y); o.z = f2b(v.z); o.w = f2b(v.w);
  out[i] = o;
}

// ------------- cast + transpose weight: W (KxN f32) -> WT (NxK bf16), * scale -------------
__global__ __launch_bounds__(256) void wtrans_kernel(const float* __restrict__ W,
                                                     u16* __restrict__ WT,
                                                     int K, int N, float scale) {
  __shared__ float t[32][33];
  int n0 = blockIdx.x * 32, k0 = blockIdx.y * 32;
  int tx = threadIdx.x, ty = threadIdx.y;  // 32 x 8
  for (int r = 0; r < 4; r++)
    t[ty + r * 8][tx] = W[(size_t)(k0 + ty + r * 8) * N + n0 + tx];
  __syncthreads();
  for (int r = 0; r < 4; r++)
    WT[(size_t)(n0 + ty + r * 8) * K + k0 + tx] = f2b(t[tx][ty + r * 8] * scale);
}

// ---------------- GEMM: C(MxN) = A(MxK) * BT(NxK)^T, m97 structure ----------------
template <bool BF16OUT>
__global__ __launch_bounds__(256) void gemm_bt_kernel(const u16* __restrict__ A,
                                                      const u16* __restrict__ BT,
                                                      void* __restrict__ Cv,
                                                      int K, int N) {
  __shared__ u16 As[128 * 32];
  __shared__ u16 Bs[128 * 32];
  const int tid = threadIdx.x;
  const int wave = tid >> 6, lane = tid & 63;
  const int quad = lane >> 4, l16 = lane & 15;
  const int wm = (wave >> 1) * 64, wn = (wave & 1) * 64;
  const size_t m0 = (size_t)blockIdx.y * 128, n0 = (size_t)blockIdx.x * 128;

  f32x4 acc[4][4] = {};
  const int srow = lane >> 2;
  const int scol = (lane & 3) * 8;
  const u16* Ag = A + (m0 + wave * 16 + srow) * (size_t)K + scol;
  const u16* Bg = BT + (n0 + wave * 16 + srow) * (size_t)K + scol;

  for (int k0 = 0; k0 < K; k0 += 32) {
    for (int rd = 0; rd < 2; rd++) {
      GLOAD16(Ag + (size_t)rd * 64 * K + k0, &As[(rd * 64 + wave * 16) * 32]);
      GLOAD16(Bg + (size_t)rd * 64 * K + k0, &Bs[(rd * 64 + wave * 16) * 32]);
    }
    __syncthreads();
    bf16x8 af[4], bf[4];
    for (int i = 0; i < 4; i++)
      af[i] = *(const bf16x8*)&As[(wm + i * 16 + l16) * 32 + quad * 8];
    for (int i = 0; i < 4; i++)
      bf[i] = *(const bf16x8*)&Bs[(wn + i * 16 + l16) * 32 + quad * 8];
    for (int mi = 0; mi < 4; mi++)
      for (int ni = 0; ni < 4; ni++)
        acc[mi][ni] = __builtin_amdgcn_mfma_f32_16x16x32_bf16(af[mi], bf[ni], acc[mi][ni], 0, 0, 0);
    __syncthreads();
  }
  for (int mi = 0; mi < 4; mi++)
    for (int ni = 0; ni < 4; ni++)
      for (int r = 0; r < 4; r++) {
        size_t row = m0 + wm + mi * 16 + quad * 4 + r;
        size_t col = n0 + wn + ni * 16 + l16;
        if (BF16OUT) ((u16*)Cv)[row * N + col] = f2b(acc[mi][ni][r]);
        else         ((float*)Cv)[row * N + col] = acc[mi][ni][r];
      }
}

// ---------------- RoPE in place on QKV cols [0,2560) ----------------
__global__ __launch_bounds__(256) void rope_kernel(u16* __restrict__ QKV,
                                                   const float* __restrict__ cs,
                                                   const float* __restrict__ sn) {
  int tid = blockIdx.x * 256 + threadIdx.x;
  int row = tid / 1280;
  int p = tid - row * 1280;
  int s = row & 2047;
  int head = p >> 6, i = p & 63;
  u16* ptr = QKV + (size_t)row * 3072 + head * 128 + i * 2;
  unsigned int v = *(unsigned int*)ptr;
  float x0 = b2f((u16)(v & 0xffff)), x1 = b2f((u16)(v >> 16));
  float c = cs[s * 64 + i], ss = sn[s * 64 + i];
  u16 o0 = f2b(x0 * c - x1 * ss);
  u16 o1 = f2b(x0 * ss + x1 * c);
  *(unsigned int*)ptr = (unsigned int)o0 | ((unsigned int)o1 << 16);
}

// ---------------- V transpose ----------------
__global__ __launch_bounds__(256) void vtrans_kernel(const u16* __restrict__ QKV,
                                                     u16* __restrict__ Vt) {
  __shared__ u16 t[32][33];
  int b = blockIdx.z >> 2, hk = blockIdx.z & 3;
  int s0 = blockIdx.x * 32, d0 = blockIdx.y * 32;
  int tx = threadIdx.x, ty = threadIdx.y;
  const u16* src = QKV + (size_t)(b * 2048 + s0) * 3072 + 2560 + hk * 128 + d0;
  for (int r = 0; r < 4; r++)
    t[ty + r * 8][tx] = src[(size_t)(ty + r * 8) * 3072 + tx];
  __syncthreads();
  u16* dst = Vt + ((size_t)((b * 4 + hk) * 128 + d0)) * 2048 + s0;
  for (int r = 0; r < 4; r++)
    dst[(size_t)(ty + r * 8) * 2048 + tx] = t[tx][ty + r * 8];
}

// ---------------- flash attention (transposed algebra) ----------------
// grid (qt=16, h=16, b=4), 256 threads = 4 waves, 32 q-rows/wave.
// Pipeline per iter kt:
//   [top] issue kreg loads (K tile kt+1, 8x dwordx4 -> 32 VGPR)
//   QK^T, softmax  (V gload_lds from iter kt-1 still in flight)
//   barrier#2: vmcnt(8) (drain V gloads, keep kreg) + lgkmcnt + s_barrier
//   P-write, PV
//   barrier#3: lgkmcnt + s_barrier
//   issue V gload_lds (tile kt+1) -> Vls; ds_write kreg -> KP
//   barrier#1': lgkmcnt + s_barrier
__global__ __launch_bounds__(256, 2) void attn_kernel(const u16* __restrict__ QKV,
                                                      const u16* __restrict__ Vt,
                                                      u16* __restrict__ AO) {
  __shared__ u16 KP[128 * 128];
  __shared__ u16 Vls[128 * 128];
  const int tid = threadIdx.x;
  const int wave = tid >> 6, lane = tid & 63;
  const int quad = lane >> 4, l16 = lane & 15;
  const int qt = blockIdx.x, h = blockIdx.y, b = blockIdx.z;
  const int hk = h >> 2;
  const int sw = l16 & 7;  // row-dependent swizzle key for this lane's rows

  // Q fragments (B-operand: n=q=l16, k=d)
  bf16x8 qf[2][4];
  {
    const u16* Qb = QKV + (size_t)(b * 2048 + qt * 128 + wave * 32) * 3072 + h * 128;
    for (int qb = 0; qb < 2; qb++)
      for (int ki = 0; ki < 4; ki++)
        qf[qb][ki] = *(const bf16x8*)(Qb + (size_t)(qb * 16 + l16) * 3072 + ki * 32 + quad * 8);
  }
  f32x4 o[8][2] = {};            // O^T: [db][qb], col=q(l16), row=d(quad*4+r)
  float m_[2] = {-1e30f, -1e30f}, l_[2] = {0.f, 0.f};

  const u16* Kg0 = QKV + 2048 + hk * 128;
  const u16* Vg0 = Vt + (size_t)((b * 4 + hk) * 128) * 2048;
  const int r4 = lane >> 4, c16 = lane & 15;

  // ---- prologue: stage tile 0 via global_load_lds (drained by syncthreads)
  {
    const u16* Kg = Kg0 + (size_t)(b * 2048) * 3072;
    const u16* Vg = Vg0;
    for (int i = 0; i < 8; i++) {
      int grp = i * 4 + wave;
      int row = grp * 4 + r4;
      int ch = c16 ^ (row & 7);
      GLOAD16(Kg + (size_t)row * 3072 + ch * 8, &KP[grp * 512]);
    }
    for (int i = 0; i < 8; i++) {
      int grp = i * 4 + wave;
      int row = grp * 4 + r4;
      int ch = c16 ^ (row & 7);
      GLOAD16(Vg + (size_t)row * 2048 + ch * 8, &Vls[grp * 512]);
    }
  }
  __syncthreads();

  // per-lane K prefetch geometry (same mapping as GLOAD16 staging:
  // row = i*16 + wave*4 + r4, ch = c16 ^ (row&7), lds dst = grp*512 + lane*8)
  const int prow = wave * 4 + r4;
  const int pch = c16 ^ (prow & 7);
  const u16* Kpf = Kg0 + ((size_t)(b * 2048 + 128) + prow) * 3072 + pch * 8;  // tile 1
  const int ldsoff = wave * 512 + lane * 8;  // u16 units; + i*2048 per chunk

  for (int kt = 0; kt < 16; kt++) {
    uint4 kreg[8];
    // issue K prefetch for tile kt+1; hides under the whole iteration
    if (kt < 15) {
#pragma unroll
      for (int i = 0; i < 8; i++)
        kreg[i] = *(const uint4*)(Kpf + (size_t)i * 49152);  // i*16*3072
    }

    // S^T = K Q^T : A = K-frag (m=key), B = Q-frag (n=q)
    f32x4 s[8][2];
    for (int kb = 0; kb < 8; kb++) {
      bf16x8 kf[4];
      int a0 = (kb * 16 + l16) * 128 + ((quad ^ sw) << 3);
      for (int ki = 0; ki < 4; ki++)
        kf[ki] = *(const bf16x8*)&KP[a0 ^ (ki * 32)];
      __builtin_amdgcn_s_setprio(1);
      for (int qb = 0; qb < 2; qb++) {
        f32x4 a = {0.f, 0.f, 0.f, 0.f};
        for (int ki = 0; ki < 4; ki++)
          a = __builtin_amdgcn_mfma_f32_16x16x32_bf16(kf[ki], qf[qb][ki], a, 0, 0, 0);
        s[kb][qb] = a;
      }
      __builtin_amdgcn_s_setprio(0);
    }

    // online softmax per q (q = qb*16 + l16); scores pre-scaled by C*log2e.
    // tree max + defer-max: skip O-rescale when no row grew by more than
    // THR=8 (log2 units); P then bounded by 2^8, fine in bf16.
    for (int qb = 0; qb < 2; qb++) {
      float mk[8];
#pragma unroll
      for (int kb = 0; kb < 8; kb++)
        mk[kb] = fmaxf(fmaxf(s[kb][qb][0], s[kb][qb][1]),
                       fmaxf(s[kb][qb][2], s[kb][qb][3]));
      float mx = fmaxf(fmaxf(fmaxf(mk[0], mk[1]), fmaxf(mk[2], mk[3])),
                       fmaxf(fmaxf(mk[4], mk[5]), fmaxf(mk[6], mk[7])));
      mx = fmaxf(mx, __shfl_xor(mx, 16, 64));
      mx = fmaxf(mx, __shfl_xor(mx, 32, 64));
      float mn = m_[qb], al = 1.0f;
      if (!__all(mx <= m_[qb] + 8.0f)) {
        mn = fmaxf(m_[qb], mx);
        al = exp2f(m_[qb] - mn);
        m_[qb] = mn;
#pragma unroll
        for (int db = 0; db < 8; db++) o[db][qb] *= al;
      }
      float rs = 0.f;
#pragma unroll
      for (int kb = 0; kb < 8; kb++) {
        float p0 = exp2f(s[kb][qb][0] - mn), p1 = exp2f(s[kb][qb][1] - mn);
        float p2 = exp2f(s[kb][qb][2] - mn), p3 = exp2f(s[kb][qb][3] - mn);
        s[kb][qb][0] = p0; s[kb][qb][1] = p1;
        s[kb][qb][2] = p2; s[kb][qb][3] = p3;
        rs += (p0 + p1) + (p2 + p3);
      }
      rs += __shfl_xor(rs, 16, 64);
      rs += __shfl_xor(rs, 32, 64);
      l_[qb] = l_[qb] * al + rs;
    }

    // barrier #2: drain the V gload_lds issued at end of iter kt-1 (counted:
    // the 8 kreg loads issued this iter are NEWER; vmcnt retires in order,
    // so <=8 outstanding  =>  all V gloads landed in Vls). Keep kreg flying.
    if (kt == 15) asm volatile("s_waitcnt vmcnt(0)" ::: "memory");
    else          asm volatile("s_waitcnt vmcnt(8)" ::: "memory");
    asm volatile("s_waitcnt lgkmcnt(0)" ::: "memory");
    __builtin_amdgcn_s_barrier();
    asm volatile("" ::: "memory");

    // P -> KP as [q][key], packed b64 (4 contiguous keys per lane)
    for (int qb = 0; qb < 2; qb++) {
      int rq = wave * 32 + qb * 16 + l16;
      for (int kb = 0; kb < 8; kb++) {
        int ch = (kb * 2 + (quad >> 1)) ^ sw;
        uint2 pv = pack4(s[kb][qb][0], s[kb][qb][1], s[kb][qb][2], s[kb][qb][3]);
        *(uint2*)&KP[rq * 128 + (ch << 3) + (quad & 1) * 4] = pv;
      }
    }
    // O^T += V^T P^T : A = V-frag (m=d), B = P-frag (n=q, own rows only)
    bf16x8 pf[2][4];
    for (int qb = 0; qb < 2; qb++) {
      int a0 = (wave * 32 + qb * 16 + l16) * 128 + ((quad ^ sw) << 3);
      for (int ki = 0; ki < 4; ki++)
        pf[qb][ki] = *(const bf16x8*)&KP[a0 ^ (ki * 32)];
    }
    for (int db = 0; db < 8; db++) {
      bf16x8 vf[4];
      int a0 = (db * 16 + l16) * 128 + ((quad ^ sw) << 3);
      for (int ki = 0; ki < 4; ki++)
        vf[ki] = *(const bf16x8*)&Vls[a0 ^ (ki * 32)];
      __builtin_amdgcn_s_setprio(1);
      for (int qb = 0; qb < 2; qb++)
        for (int ki = 0; ki < 4; ki++)
          o[db][qb] = __builtin_amdgcn_mfma_f32_16x16x32_bf16(vf[ki], pf[qb][ki], o[db][qb], 0, 0, 0);
      __builtin_amdgcn_s_setprio(0);
    }

    bar_sync();  // #3: all waves' V+P reads done before restage

    if (kt < 15) {
      // V tile kt+1 via global_load_lds into Vls (free after barrier #3);
      // stays in flight until barrier #2 of the next iter.
      {
        const u16* Vg = Vg0 + (kt + 1) * 128;
        for (int i = 0; i < 8; i++) {
          int grp = i * 4 + wave;
          int row = grp * 4 + r4;
          int ch = c16 ^ (row & 7);
          GLOAD16(Vg + (size_t)row * 2048 + ch * 8, &Vls[grp * 512]);
        }
      }
      __builtin_amdgcn_sched_barrier(0);  // pin V-issue before the kreg drain
      // K tile kt+1: regs -> LDS (compiler waits vmcnt for kreg only)
#pragma unroll
      for (int i = 0; i < 8; i++) *(uint4*)&KP[ldsoff + i * 2048] = kreg[i];
      Kpf += 393216;  // 128*3072
      bar_sync();  // #1': K tile visible to all waves
    }
  }

  // epilogue: O^T/l -> LDS [q][d] packed b64 -> coalesced global store
  float inv[2] = {1.0f / l_[0], 1.0f / l_[1]};
  for (int qb = 0; qb < 2; qb++) {
    int rq = wave * 32 + qb * 16 + l16;
    for (int db = 0; db < 8; db++) {
      int ch = (db * 2 + (quad >> 1)) ^ sw;
      uint2 pv = pack4(o[db][qb][0] * inv[qb], o[db][qb][1] * inv[qb],
                       o[db][qb][2] * inv[qb], o[db][qb][3] * inv[qb]);
      *(uint2*)&KP[rq * 128 + (ch << 3) + (quad & 1) * 4] = pv;
    }
  }
  __syncthreads();
  u16* Ab = AO + (size_t)(b * 2048 + qt * 128) * 2048 + h * 128;
  for (int i = 0; i < 8; i++) {
    int row = i * 16 + (tid >> 4);
    int seg = tid & 15;
    int pc = seg ^ (row & 7);
    *(uint4*)(Ab + (size_t)row * 2048 + seg * 8) = *(const uint4*)&KP[row * 128 + pc * 8];
  }
}

// ---------------- launch ----------------
extern "C" void kernel_launch(void* const* d_in, const int* in_sizes, int n_in,
                              void* d_out, int out_size, void* d_ws, size_t ws_size,
                              hipStream_t stream) {
  (void)in_sizes; (void)n_in; (void)out_size; (void)ws_size;
  const float* x    = (const float*)d_in[0];
  const float* fcos = (const float*)d_in[1];
  const float* fsin = (const float*)d_in[2];
  const float* wq   = (const float*)d_in[3];
  const float* wk   = (const float*)d_in[4];
  const float* wv   = (const float*)d_in[5];
  const float* wo   = (const float*)d_in[6];

  char* w = (char*)d_ws;
  u16* xb  = (u16*)w;                               // 8192x2048 bf16, reused as attn_out
  u16* wT  = (u16*)(w + 33554432);                  // 3072x2048 bf16
  u16* woT = (u16*)(w + 33554432 + 12582912);       // 2048x2048 bf16
  u16* QKV = (u16*)(w + 33554432 + 12582912 + 8388608);            // 8192x3072 bf16
  u16* Vt  = (u16*)(w + 33554432 + 12582912 + 8388608 + 50331648); // 16x128x2048 bf16
  u16* AO  = xb;

  const float C = 0.08838834764831845f * 1.44269504088896340f;  // 1/sqrt(128)*log2(e)

  cast_x_kernel<<<16384, 256, 0, stream>>>((const float4*)x, (ushort4*)xb);
  wtrans_kernel<<<dim3(64, 64), dim3(32, 8), 0, stream>>>(wq, wT, 2048, 2048, C);
  wtrans_kernel<<<dim3(16, 64), dim3(32, 8), 0, stream>>>(wk, wT + (size_t)2048 * 2048, 2048, 512, 1.0f);
  wtrans_kernel<<<dim3(16, 64), dim3(32, 8), 0, stream>>>(wv, wT + (size_t)2560 * 2048, 2048, 512, 1.0f);
  wtrans_kernel<<<dim3(64, 64), dim3(32, 8), 0, stream>>>(wo, woT, 2048, 2048, 1.0f);

  gemm_bt_kernel<true><<<dim3(24, 64), 256, 0, stream>>>(xb, wT, QKV, 2048, 3072);
  rope_kernel<<<40960, 256, 0, stream>>>(QKV, fcos, fsin);
  vtrans_kernel<<<dim3(64, 4, 16), dim3(32, 8), 0, stream>>>(QKV, Vt);
  attn_kernel<<<dim3(16, 16, 4), 256, 0, stream>>>(QKV, Vt, AO);
  gemm_bt_kernel<false><<<dim3(16, 64), 256, 0, stream>>>(AO, woT, (float*)d_out, 2048, 2048);
}

// Round 3
// 667.706 us; speedup vs baseline: 1.1296x; 1.0020x over previous
//
#include <hip/hip_runtime.h>
#include <stdint.h>

// Attention_48945447306134 on MI355X.
//   GEMM1: QKV = xb @ [wq*C|wk|wv]^T  (wq pre-scaled by softmax_scale*log2e)
//   RoPE in place; V pre-transposed to Vt[b][hk][d][s]
//   Flash attention, TRANSPOSED algebra: S^T = K Q^T, O^T = V^T P^T
//   This rev (spill fix): fuse exp->bf16 pack (s dies pre-barrier, pk=32 regs);
//   kreg K-prefetch issued AFTER barrier#2 (never co-live with s);
//   V staged via global_load_lds at iter tail, drained by vmcnt(0) at
//   barrier#2. Keeps: defer-max THR=8, cvt_pk packing, tree reductions,
//   setprio around MFMA clusters.
//   GEMM2: out = attn @ woT (fp32 out)

typedef unsigned short u16;
typedef __bf16 bf16x8 __attribute__((ext_vector_type(8)));
typedef float  f32x4  __attribute__((ext_vector_type(4)));

#define GLOAD16(gp, lp)                                                        \
  __builtin_amdgcn_global_load_lds(                                            \
      (const __attribute__((address_space(1))) void*)(gp),                     \
      (__attribute__((address_space(3))) void*)(lp), 16, 0, 0)

__device__ __forceinline__ u16 f2b(float f) {  // RNE f32->bf16
  union { float f; uint32_t u; } v; v.f = f;
  uint32_t r = v.u + 0x7FFFu + ((v.u >> 16) & 1u);
  return (u16)(r >> 16);
}
__device__ __forceinline__ float b2f(u16 h) {
  union { uint32_t u; float f; } v; v.u = ((uint32_t)h) << 16;
  return v.f;
}
// RNE pack via HW instruction
__device__ __forceinline__ uint2 pack4(float a, float b, float c, float d) {
  uint2 r;
  asm("v_cvt_pk_bf16_f32 %0, %1, %2" : "=v"(r.x) : "v"(a), "v"(b));
  asm("v_cvt_pk_bf16_f32 %0, %1, %2" : "=v"(r.y) : "v"(c), "v"(d));
  return r;
}

// block barrier that does NOT drain vmcnt (keeps prefetch loads in flight).
__device__ __forceinline__ void bar_sync() {
  asm volatile("s_waitcnt lgkmcnt(0)" ::: "memory");
  __builtin_amdgcn_s_barrier();
  asm volatile("" ::: "memory");
}

// ---------------- cast x -> bf16 ----------------
__global__ __launch_bounds__(256) void cast_x_kernel(const float4* __restrict__ in,
                                                     ushort4* __restrict__ out) {
  int i = blockIdx.x * 256 + threadIdx.x;
  float4 v = in[i];
  ushort4 o;
  o.x = f2b(v.x); o.y = f2b(v.y); o.z = f2b(v.z); o.w = f2b(v.w);
  out[i] = o;
}

// ------------- cast + transpose weight: W (KxN f32) -> WT (NxK bf16), * scale -------------
__global__ __launch_bounds__(256) void wtrans_kernel(const float* __restrict__ W,
                                                     u16* __restrict__ WT,
                                                     int K, int N, float scale) {
  __shared__ float t[32][33];
  int n0 = blockIdx.x * 32, k0 = blockIdx.y * 32;
  int tx = threadIdx.x, ty = threadIdx.y;  // 32 x 8
  for (int r = 0; r < 4; r++)
    t[ty + r * 8][tx] = W[(size_t)(k0 + ty + r * 8) * N + n0 + tx];
  __syncthreads();
  for (int r = 0; r < 4; r++)
    WT[(size_t)(n0 + ty + r * 8) * K + k0 + tx] = f2b(t[tx][ty + r * 8] * scale);
}

// ---------------- GEMM: C(MxN) = A(MxK) * BT(NxK)^T, m97 structure ----------------
template <bool BF16OUT>
__global__ __launch_bounds__(256) void gemm_bt_kernel(const u16* __restrict__ A,
                                                      const u16* __restrict__ BT,
                                                      void* __restrict__ Cv,
                                                      int K, int N) {
  __shared__ u16 As[128 * 32];
  __shared__ u16 Bs[128 * 32];
  const int tid = threadIdx.x;
  const int wave = tid >> 6, lane = tid & 63;
  const int quad = lane >> 4, l16 = lane & 15;
  const int wm = (wave >> 1) * 64, wn = (wave & 1) * 64;
  const size_t m0 = (size_t)blockIdx.y * 128, n0 = (size_t)blockIdx.x * 128;

  f32x4 acc[4][4] = {};
  const int srow = lane >> 2;
  const int scol = (lane & 3) * 8;
  const u16* Ag = A + (m0 + wave * 16 + srow) * (size_t)K + scol;
  const u16* Bg = BT + (n0 + wave * 16 + srow) * (size_t)K + scol;

  for (int k0 = 0; k0 < K; k0 += 32) {
    for (int rd = 0; rd < 2; rd++) {
      GLOAD16(Ag + (size_t)rd * 64 * K + k0, &As[(rd * 64 + wave * 16) * 32]);
      GLOAD16(Bg + (size_t)rd * 64 * K + k0, &Bs[(rd * 64 + wave * 16) * 32]);
    }
    __syncthreads();
    bf16x8 af[4], bf[4];
    for (int i = 0; i < 4; i++)
      af[i] = *(const bf16x8*)&As[(wm + i * 16 + l16) * 32 + quad * 8];
    for (int i = 0; i < 4; i++)
      bf[i] = *(const bf16x8*)&Bs[(wn + i * 16 + l16) * 32 + quad * 8];
    for (int mi = 0; mi < 4; mi++)
      for (int ni = 0; ni < 4; ni++)
        acc[mi][ni] = __builtin_amdgcn_mfma_f32_16x16x32_bf16(af[mi], bf[ni], acc[mi][ni], 0, 0, 0);
    __syncthreads();
  }
  for (int mi = 0; mi < 4; mi++)
    for (int ni = 0; ni < 4; ni++)
      for (int r = 0; r < 4; r++) {
        size_t row = m0 + wm + mi * 16 + quad * 4 + r;
        size_t col = n0 + wn + ni * 16 + l16;
        if (BF16OUT) ((u16*)Cv)[row * N + col] = f2b(acc[mi][ni][r]);
        else         ((float*)Cv)[row * N + col] = acc[mi][ni][r];
      }
}

// ---------------- RoPE in place on QKV cols [0,2560) ----------------
__global__ __launch_bounds__(256) void rope_kernel(u16* __restrict__ QKV,
                                                   const float* __restrict__ cs,
                                                   const float* __restrict__ sn) {
  int tid = blockIdx.x * 256 + threadIdx.x;
  int row = tid / 1280;
  int p = tid - row * 1280;
  int s = row & 2047;
  int head = p >> 6, i = p & 63;
  u16* ptr = QKV + (size_t)row * 3072 + head * 128 + i * 2;
  unsigned int v = *(unsigned int*)ptr;
  float x0 = b2f((u16)(v & 0xffff)), x1 = b2f((u16)(v >> 16));
  float c = cs[s * 64 + i], ss = sn[s * 64 + i];
  u16 o0 = f2b(x0 * c - x1 * ss);
  u16 o1 = f2b(x0 * ss + x1 * c);
  *(unsigned int*)ptr = (unsigned int)o0 | ((unsigned int)o1 << 16);
}

// ---------------- V transpose ----------------
__global__ __launch_bounds__(256) void vtrans_kernel(const u16* __restrict__ QKV,
                                                     u16* __restrict__ Vt) {
  __shared__ u16 t[32][33];
  int b = blockIdx.z >> 2, hk = blockIdx.z & 3;
  int s0 = blockIdx.x * 32, d0 = blockIdx.y * 32;
  int tx = threadIdx.x, ty = threadIdx.y;
  const u16* src = QKV + (size_t)(b * 2048 + s0) * 3072 + 2560 + hk * 128 + d0;
  for (int r = 0; r < 4; r++)
    t[ty + r * 8][tx] = src[(size_t)(ty + r * 8) * 3072 + tx];
  __syncthreads();
  u16* dst = Vt + ((size_t)((b * 4 + hk) * 128 + d0)) * 2048 + s0;
  for (int r = 0; r < 4; r++)
    dst[(size_t)(ty + r * 8) * 2048 + tx] = t[tx][ty + r * 8];
}

// ---------------- flash attention (transposed algebra) ----------------
// grid (qt=16, h=16, b=4), 256 threads = 4 waves, 32 q-rows/wave.
// Pipeline per iter kt:
//   QK^T, softmax fused with exp->bf16 pack (pk, 32 regs; s dies here)
//     (V gload_lds from iter kt-1 still in flight)
//   barrier#2: vmcnt(0) (only V outstanding) + lgkm + s_barrier
//   issue kreg loads (K tile kt+1, 8x dwordx4) -- cover = P-write + PV
//   P-write from pk, PV
//   barrier#3: lgkm + s_barrier
//   ds_write kreg -> KP (auto vmcnt drains kreg only); issue V gload_lds
//   barrier#1': lgkm only (V stays in flight)
__global__ __launch_bounds__(256, 2) void attn_kernel(const u16* __restrict__ QKV,
                                                      const u16* __restrict__ Vt,
                                                      u16* __restrict__ AO) {
  __shared__ u16 KP[128 * 128];
  __shared__ u16 Vls[128 * 128];
  const int tid = threadIdx.x;
  const int wave = tid >> 6, lane = tid & 63;
  const int quad = lane >> 4, l16 = lane & 15;
  const int qt = blockIdx.x, h = blockIdx.y, b = blockIdx.z;
  const int hk = h >> 2;
  const int sw = l16 & 7;  // row-dependent swizzle key for this lane's rows

  // Q fragments (B-operand: n=q=l16, k=d)
  bf16x8 qf[2][4];
  {
    const u16* Qb = QKV + (size_t)(b * 2048 + qt * 128 + wave * 32) * 3072 + h * 128;
    for (int qb = 0; qb < 2; qb++)
      for (int ki = 0; ki < 4; ki++)
        qf[qb][ki] = *(const bf16x8*)(Qb + (size_t)(qb * 16 + l16) * 3072 + ki * 32 + quad * 8);
  }
  f32x4 o[8][2] = {};            // O^T: [db][qb], col=q(l16), row=d(quad*4+r)
  float m_[2] = {-1e30f, -1e30f}, l_[2] = {0.f, 0.f};

  const u16* Kg0 = QKV + 2048 + hk * 128;
  const u16* Vg0 = Vt + (size_t)((b * 4 + hk) * 128) * 2048;
  const int r4 = lane >> 4, c16 = lane & 15;

  // ---- prologue: stage tile 0 via global_load_lds (drained by syncthreads)
  {
    const u16* Kg = Kg0 + (size_t)(b * 2048) * 3072;
    const u16* Vg = Vg0;
    for (int i = 0; i < 8; i++) {
      int grp = i * 4 + wave;
      int row = grp * 4 + r4;
      int ch = c16 ^ (row & 7);
      GLOAD16(Kg + (size_t)row * 3072 + ch * 8, &KP[grp * 512]);
    }
    for (int i = 0; i < 8; i++) {
      int grp = i * 4 + wave;
      int row = grp * 4 + r4;
      int ch = c16 ^ (row & 7);
      GLOAD16(Vg + (size_t)row * 2048 + ch * 8, &Vls[grp * 512]);
    }
  }
  __syncthreads();

  // per-lane K prefetch geometry (same mapping as GLOAD16 staging:
  // row = i*16 + wave*4 + r4, ch = c16 ^ (row&7), lds dst = grp*512 + lane*8)
  const int prow = wave * 4 + r4;
  const int pch = c16 ^ (prow & 7);
  const u16* Kpf = Kg0 + ((size_t)(b * 2048 + 128) + prow) * 3072 + pch * 8;  // tile 1
  const int ldsoff = wave * 512 + lane * 8;  // u16 units; + i*2048 per chunk

  for (int kt = 0; kt < 16; kt++) {
    // S^T = K Q^T : A = K-frag (m=key), B = Q-frag (n=q)
    f32x4 s[8][2];
    for (int kb = 0; kb < 8; kb++) {
      bf16x8 kf[4];
      int a0 = (kb * 16 + l16) * 128 + ((quad ^ sw) << 3);
      for (int ki = 0; ki < 4; ki++)
        kf[ki] = *(const bf16x8*)&KP[a0 ^ (ki * 32)];
      __builtin_amdgcn_s_setprio(1);
      for (int qb = 0; qb < 2; qb++) {
        f32x4 a = {0.f, 0.f, 0.f, 0.f};
        for (int ki = 0; ki < 4; ki++)
          a = __builtin_amdgcn_mfma_f32_16x16x32_bf16(kf[ki], qf[qb][ki], a, 0, 0, 0);
        s[kb][qb] = a;
      }
      __builtin_amdgcn_s_setprio(0);
    }

    // online softmax per q (q = qb*16 + l16); scores pre-scaled by C*log2e.
    // tree max + defer-max (THR=8 log2 units); exp fused with bf16 pack so
    // the 64 f32 scores die here and only pk (32 regs) crosses barrier#2.
    uint2 pk[2][8];
    float alch[2];
    for (int qb = 0; qb < 2; qb++) {
      float mk[8];
#pragma unroll
      for (int kb = 0; kb < 8; kb++)
        mk[kb] = fmaxf(fmaxf(s[kb][qb][0], s[kb][qb][1]),
                       fmaxf(s[kb][qb][2], s[kb][qb][3]));
      float mx = fmaxf(fmaxf(fmaxf(mk[0], mk[1]), fmaxf(mk[2], mk[3])),
                       fmaxf(fmaxf(mk[4], mk[5]), fmaxf(mk[6], mk[7])));
      mx = fmaxf(mx, __shfl_xor(mx, 16, 64));
      mx = fmaxf(mx, __shfl_xor(mx, 32, 64));
      float mn = m_[qb], al = 1.0f;
      if (!__all(mx <= m_[qb] + 8.0f)) {
        mn = fmaxf(m_[qb], mx);
        al = exp2f(m_[qb] - mn);
        m_[qb] = mn;
      }
      alch[qb] = al;
      float rs = 0.f;
#pragma unroll
      for (int kb = 0; kb < 8; kb++) {
        float p0 = exp2f(s[kb][qb][0] - mn), p1 = exp2f(s[kb][qb][1] - mn);
        float p2 = exp2f(s[kb][qb][2] - mn), p3 = exp2f(s[kb][qb][3] - mn);
        pk[qb][kb] = pack4(p0, p1, p2, p3);
        rs += (p0 + p1) + (p2 + p3);
      }
      rs += __shfl_xor(rs, 16, 64);
      rs += __shfl_xor(rs, 32, 64);
      l_[qb] = l_[qb] * al + rs;
    }
    // O-rescale (only when some row deferred past THR)
    if (alch[0] != 1.0f || alch[1] != 1.0f) {
#pragma unroll
      for (int db = 0; db < 8; db++) {
        o[db][0] *= alch[0];
        o[db][1] *= alch[1];
      }
    }

    // barrier #2: only the V gload_lds from iter kt-1 are outstanding
    asm volatile("s_waitcnt vmcnt(0)" ::: "memory");
    asm volatile("s_waitcnt lgkmcnt(0)" ::: "memory");
    __builtin_amdgcn_s_barrier();
    asm volatile("" ::: "memory");

    // issue K prefetch for tile kt+1 (regs); cover = P-write + PV
    uint4 kreg[8];
    if (kt < 15) {
#pragma unroll
      for (int i = 0; i < 8; i++)
        kreg[i] = *(const uint4*)(Kpf + (size_t)i * 49152);  // i*16*3072
    }

    // P -> KP as [q][key], packed b64 (4 contiguous keys per lane)
    for (int qb = 0; qb < 2; qb++) {
      int rq = wave * 32 + qb * 16 + l16;
      for (int kb = 0; kb < 8; kb++) {
        int ch = (kb * 2 + (quad >> 1)) ^ sw;
        *(uint2*)&KP[rq * 128 + (ch << 3) + (quad & 1) * 4] = pk[qb][kb];
      }
    }
    // O^T += V^T P^T : A = V-frag (m=d), B = P-frag (n=q, own rows only)
    bf16x8 pf[2][4];
    for (int qb = 0; qb < 2; qb++) {
      int a0 = (wave * 32 + qb * 16 + l16) * 128 + ((quad ^ sw) << 3);
      for (int ki = 0; ki < 4; ki++)
        pf[qb][ki] = *(const bf16x8*)&KP[a0 ^ (ki * 32)];
    }
    for (int db = 0; db < 8; db++) {
      bf16x8 vf[4];
      int a0 = (db * 16 + l16) * 128 + ((quad ^ sw) << 3);
      for (int ki = 0; ki < 4; ki++)
        vf[ki] = *(const bf16x8*)&Vls[a0 ^ (ki * 32)];
      __builtin_amdgcn_s_setprio(1);
      for (int qb = 0; qb < 2; qb++)
        for (int ki = 0; ki < 4; ki++)
          o[db][qb] = __builtin_amdgcn_mfma_f32_16x16x32_bf16(vf[ki], pf[qb][ki], o[db][qb], 0, 0, 0);
      __builtin_amdgcn_s_setprio(0);
    }

    bar_sync();  // #3: all waves' V+P reads done before restage

    if (kt < 15) {
      // K tile kt+1: regs -> LDS (auto vmcnt wait counts kreg only)
#pragma unroll
      for (int i = 0; i < 8; i++) *(uint4*)&KP[ldsoff + i * 2048] = kreg[i];
      Kpf += 393216;  // 128*3072
      __builtin_amdgcn_sched_barrier(0);
      // V tile kt+1 via global_load_lds into Vls; stays in flight until
      // barrier#2 of the next iter.
      {
        const u16* Vg = Vg0 + (kt + 1) * 128;
        for (int i = 0; i < 8; i++) {
          int grp = i * 4 + wave;
          int row = grp * 4 + r4;
          int ch = c16 ^ (row & 7);
          GLOAD16(Vg + (size_t)row * 2048 + ch * 8, &Vls[grp * 512]);
        }
      }
      bar_sync();  // #1': K tile visible to all waves; V keeps flying
    }
  }

  // epilogue: O^T/l -> LDS [q][d] packed b64 -> coalesced global store
  float inv[2] = {1.0f / l_[0], 1.0f / l_[1]};
  for (int qb = 0; qb < 2; qb++) {
    int rq = wave * 32 + qb * 16 + l16;
    for (int db = 0; db < 8; db++) {
      int ch = (db * 2 + (quad >> 1)) ^ sw;
      uint2 pv = pack4(o[db][qb][0] * inv[qb], o[db][qb][1] * inv[qb],
                       o[db][qb][2] * inv[qb], o[db][qb][3] * inv[qb]);
      *(uint2*)&KP[rq * 128 + (ch << 3) + (quad & 1) * 4] = pv;
    }
  }
  __syncthreads();
  u16* Ab = AO + (size_t)(b * 2048 + qt * 128) * 2048 + h * 128;
  for (int i = 0; i < 8; i++) {
    int row = i * 16 + (tid >> 4);
    int seg = tid & 15;
    int pc = seg ^ (row & 7);
    *(uint4*)(Ab + (size_t)row * 2048 + seg * 8) = *(const uint4*)&KP[row * 128 + pc * 8];
  }
}

// ---------------- launch ----------------
extern "C" void kernel_launch(void* const* d_in, const int* in_sizes, int n_in,
                              void* d_out, int out_size, void* d_ws, size_t ws_size,
                              hipStream_t stream) {
  (void)in_sizes; (void)n_in; (void)out_size; (void)ws_size;
  const float* x    = (const float*)d_in[0];
  const float* fcos = (const float*)d_in[1];
  const float* fsin = (const float*)d_in[2];
  const float* wq   = (const float*)d_in[3];
  const float* wk   = (const float*)d_in[4];
  const float* wv   = (const float*)d_in[5];
  const float* wo   = (const float*)d_in[6];

  char* w = (char*)d_ws;
  u16* xb  = (u16*)w;                               // 8192x2048 bf16, reused as attn_out
  u16* wT  = (u16*)(w + 33554432);                  // 3072x2048 bf16
  u16* woT = (u16*)(w + 33554432 + 12582912);       // 2048x2048 bf16
  u16* QKV = (u16*)(w + 33554432 + 12582912 + 8388608);            // 8192x3072 bf16
  u16* Vt  = (u16*)(w + 33554432 + 12582912 + 8388608 + 50331648); // 16x128x2048 bf16
  u16* AO  = xb;

  const float C = 0.08838834764831845f * 1.44269504088896340f;  // 1/sqrt(128)*log2(e)

  cast_x_kernel<<<16384, 256, 0, stream>>>((const float4*)x, (ushort4*)xb);
  wtrans_kernel<<<dim3(64, 64), dim3(32, 8), 0, stream>>>(wq, wT, 2048, 2048, C);
  wtrans_kernel<<<dim3(16, 64), dim3(32, 8), 0, stream>>>(wk, wT + (size_t)2048 * 2048, 2048, 512, 1.0f);
  wtrans_kernel<<<dim3(16, 64), dim3(32, 8), 0, stream>>>(wv, wT + (size_t)2560 * 2048, 2048, 512, 1.0f);
  wtrans_kernel<<<dim3(64, 64), dim3(32, 8), 0, stream>>>(wo, woT, 2048, 2048, 1.0f);

  gemm_bt_kernel<true><<<dim3(24, 64), 256, 0, stream>>>(xb, wT, QKV, 2048, 3072);
  rope_kernel<<<40960, 256, 0, stream>>>(QKV, fcos, fsin);
  vtrans_kernel<<<dim3(64, 4, 16), dim3(32, 8), 0, stream>>>(QKV, Vt);
  attn_kernel<<<dim3(16, 16, 4), 256, 0, stream>>>(QKV, Vt, AO);
  gemm_bt_kernel<false><<<dim3(16, 64), 256, 0, stream>>>(AO, woT, (float*)d_out, 2048, 2048);
}

// Round 5
// 618.125 us; speedup vs baseline: 1.2203x; 1.0802x over previous
//
#include <hip/hip_runtime.h>
#include <stdint.h>

// Attention_48945447306134 on MI355X.
//   GEMM1: QKV = xb @ [wq*C|wk|wv]^T  (wq pre-scaled by softmax_scale*log2e)
//   RoPE in place; V pre-transposed to Vt[b][hk][d][s]
//   Flash attention, TRANSPOSED algebra: S^T = K Q^T, O^T = V^T P^T
//   This rev (resubmit of r4 after container-level infra failure; audited for
//   barrier divergence / OOB DMA / exchange mapping -- all clean):
//   P never touches LDS -- in-register cross-quad exchange via ds_bpermute
//   builds the PV B-fragments directly from the QK^T output. KP holds K only,
//   so K_next restages via global_load_lds right after the post-QK barrier
//   (cover = softmax+exchange+PV); V_next issues at loop top (cover =
//   QK+softmax), drained by counted vmcnt(8). No kreg, no P-write/read,
//   arch regs fit the 128 cap imposed by the 128-AGPR accumulator half ->
//   no scratch spill. Keeps: defer-max THR=8, cvt_pk packing, tree
//   reductions, setprio around MFMA clusters.
//   GEMM2: out = attn @ woT (fp32 out)

typedef unsigned short u16;
typedef __bf16 bf16x8 __attribute__((ext_vector_type(8)));
typedef float  f32x4  __attribute__((ext_vector_type(4)));

#define GLOAD16(gp, lp)                                                        \
  __builtin_amdgcn_global_load_lds(                                            \
      (const __attribute__((address_space(1))) void*)(gp),                     \
      (__attribute__((address_space(3))) void*)(lp), 16, 0, 0)

__device__ __forceinline__ u16 f2b(float f) {  // RNE f32->bf16
  union { float f; uint32_t u; } v; v.f = f;
  uint32_t r = v.u + 0x7FFFu + ((v.u >> 16) & 1u);
  return (u16)(r >> 16);
}
__device__ __forceinline__ float b2f(u16 h) {
  union { uint32_t u; float f; } v; v.u = ((uint32_t)h) << 16;
  return v.f;
}
// RNE pack via HW instruction
__device__ __forceinline__ uint2 pack4(float a, float b, float c, float d) {
  uint2 r;
  asm("v_cvt_pk_bf16_f32 %0, %1, %2" : "=v"(r.x) : "v"(a), "v"(b));
  asm("v_cvt_pk_bf16_f32 %0, %1, %2" : "=v"(r.y) : "v"(c), "v"(d));
  return r;
}

// block barrier that does NOT drain vmcnt (keeps staging loads in flight).
__device__ __forceinline__ void bar_sync() {
  asm volatile("s_waitcnt lgkmcnt(0)" ::: "memory");
  __builtin_amdgcn_s_barrier();
  asm volatile("" ::: "memory");
}

// ---------------- cast x -> bf16 ----------------
__global__ __launch_bounds__(256) void cast_x_kernel(const float4* __restrict__ in,
                                                     ushort4* __restrict__ out) {
  int i = blockIdx.x * 256 + threadIdx.x;
  float4 v = in[i];
  ushort4 o;
  o.x = f2b(v.x); o.y = f2b(v.y); o.z = f2b(v.z); o.w = f2b(v.w);
  out[i] = o;
}

// ------------- cast + transpose weight: W (KxN f32) -> WT (NxK bf16), * scale -------------
__global__ __launch_bounds__(256) void wtrans_kernel(const float* __restrict__ W,
                                                     u16* __restrict__ WT,
                                                     int K, int N, float scale) {
  __shared__ float t[32][33];
  int n0 = blockIdx.x * 32, k0 = blockIdx.y * 32;
  int tx = threadIdx.x, ty = threadIdx.y;  // 32 x 8
  for (int r = 0; r < 4; r++)
    t[ty + r * 8][tx] = W[(size_t)(k0 + ty + r * 8) * N + n0 + tx];
  __syncthreads();
  for (int r = 0; r < 4; r++)
    WT[(size_t)(n0 + ty + r * 8) * K + k0 + tx] = f2b(t[tx][ty + r * 8] * scale);
}

// ---------------- GEMM: C(MxN) = A(MxK) * BT(NxK)^T, m97 structure ----------------
template <bool BF16OUT>
__global__ __launch_bounds__(256) void gemm_bt_kernel(const u16* __restrict__ A,
                                                      const u16* __restrict__ BT,
                                                      void* __restrict__ Cv,
                                                      int K, int N) {
  __shared__ u16 As[128 * 32];
  __shared__ u16 Bs[128 * 32];
  const int tid = threadIdx.x;
  const int wave = tid >> 6, lane = tid & 63;
  const int quad = lane >> 4, l16 = lane & 15;
  const int wm = (wave >> 1) * 64, wn = (wave & 1) * 64;
  const size_t m0 = (size_t)blockIdx.y * 128, n0 = (size_t)blockIdx.x * 128;

  f32x4 acc[4][4] = {};
  const int srow = lane >> 2;
  const int scol = (lane & 3) * 8;
  const u16* Ag = A + (m0 + wave * 16 + srow) * (size_t)K + scol;
  const u16* Bg = BT + (n0 + wave * 16 + srow) * (size_t)K + scol;

  for (int k0 = 0; k0 < K; k0 += 32) {
    for (int rd = 0; rd < 2; rd++) {
      GLOAD16(Ag + (size_t)rd * 64 * K + k0, &As[(rd * 64 + wave * 16) * 32]);
      GLOAD16(Bg + (size_t)rd * 64 * K + k0, &Bs[(rd * 64 + wave * 16) * 32]);
    }
    __syncthreads();
    bf16x8 af[4], bf[4];
    for (int i = 0; i < 4; i++)
      af[i] = *(const bf16x8*)&As[(wm + i * 16 + l16) * 32 + quad * 8];
    for (int i = 0; i < 4; i++)
      bf[i] = *(const bf16x8*)&Bs[(wn + i * 16 + l16) * 32 + quad * 8];
    for (int mi = 0; mi < 4; mi++)
      for (int ni = 0; ni < 4; ni++)
        acc[mi][ni] = __builtin_amdgcn_mfma_f32_16x16x32_bf16(af[mi], bf[ni], acc[mi][ni], 0, 0, 0);
    __syncthreads();
  }
  for (int mi = 0; mi < 4; mi++)
    for (int ni = 0; ni < 4; ni++)
      for (int r = 0; r < 4; r++) {
        size_t row = m0 + wm + mi * 16 + quad * 4 + r;
        size_t col = n0 + wn + ni * 16 + l16;
        if (BF16OUT) ((u16*)Cv)[row * N + col] = f2b(acc[mi][ni][r]);
        else         ((float*)Cv)[row * N + col] = acc[mi][ni][r];
      }
}

// ---------------- RoPE in place on QKV cols [0,2560) ----------------
__global__ __launch_bounds__(256) void rope_kernel(u16* __restrict__ QKV,
                                                   const float* __restrict__ cs,
                                                   const float* __restrict__ sn) {
  int tid = blockIdx.x * 256 + threadIdx.x;
  int row = tid / 1280;
  int p = tid - row * 1280;
  int s = row & 2047;
  int head = p >> 6, i = p & 63;
  u16* ptr = QKV + (size_t)row * 3072 + head * 128 + i * 2;
  unsigned int v = *(unsigned int*)ptr;
  float x0 = b2f((u16)(v & 0xffff)), x1 = b2f((u16)(v >> 16));
  float c = cs[s * 64 + i], ss = sn[s * 64 + i];
  u16 o0 = f2b(x0 * c - x1 * ss);
  u16 o1 = f2b(x0 * ss + x1 * c);
  *(unsigned int*)ptr = (unsigned int)o0 | ((unsigned int)o1 << 16);
}

// ---------------- V transpose ----------------
__global__ __launch_bounds__(256) void vtrans_kernel(const u16* __restrict__ QKV,
                                                     u16* __restrict__ Vt) {
  __shared__ u16 t[32][33];
  int b = blockIdx.z >> 2, hk = blockIdx.z & 3;
  int s0 = blockIdx.x * 32, d0 = blockIdx.y * 32;
  int tx = threadIdx.x, ty = threadIdx.y;
  const u16* src = QKV + (size_t)(b * 2048 + s0) * 3072 + 2560 + hk * 128 + d0;
  for (int r = 0; r < 4; r++)
    t[ty + r * 8][tx] = src[(size_t)(ty + r * 8) * 3072 + tx];
  __syncthreads();
  u16* dst = Vt + ((size_t)((b * 4 + hk) * 128 + d0)) * 2048 + s0;
  for (int r = 0; r < 4; r++)
    dst[(size_t)(ty + r * 8) * 2048 + tx] = t[tx][ty + r * 8];
}

// ---------------- flash attention (transposed algebra, P in registers) ------
// grid (qt=16, h=16, b=4), 256 threads = 4 waves, 32 q-rows/wave.
// Per iter kt:
//   [top] if kt>0: issue V_kt gload_lds (Vls free since BARRIER_END(kt-1))
//   QK^T (reads KP = K_kt)
//   BARRIER_A (lgkm+bar): all waves done reading K_kt
//   if kt<15: issue K_{kt+1} gload_lds -> KP  (cover: softmax+exchange+PV)
//   softmax (tree max, defer-max) + exp->bf16 pack -> u[8] (uint2)
//   exchange: ds_bpermute cross-quad -> pf[qb][ki]  (P stays in registers)
//   BARRIER_B: vmcnt(8) (drain V_kt, keep K flying) + lgkm + bar
//   PV (reads Vls, pf)
//   BARRIER_END: vmcnt(0) (K_{kt+1} landed; was covered) + lgkm + bar
__global__ __launch_bounds__(256, 2) void attn_kernel(const u16* __restrict__ QKV,
                                                      const u16* __restrict__ Vt,
                                                      u16* __restrict__ AO) {
  __shared__ u16 KP[128 * 128];
  __shared__ u16 Vls[128 * 128];
  const int tid = threadIdx.x;
  const int wave = tid >> 6, lane = tid & 63;
  const int quad = lane >> 4, l16 = lane & 15;
  const int qt = blockIdx.x, h = blockIdx.y, b = blockIdx.z;
  const int hk = h >> 2;
  const int sw = l16 & 7;  // row-dependent swizzle key for this lane's rows

  // Q fragments (B-operand: n=q=l16, k=d)
  bf16x8 qf[2][4];
  {
    const u16* Qb = QKV + (size_t)(b * 2048 + qt * 128 + wave * 32) * 3072 + h * 128;
    for (int qb = 0; qb < 2; qb++)
      for (int ki = 0; ki < 4; ki++)
        qf[qb][ki] = *(const bf16x8*)(Qb + (size_t)(qb * 16 + l16) * 3072 + ki * 32 + quad * 8);
  }
  f32x4 o[8][2] = {};            // O^T: [db][qb], col=q(l16), row=d(quad*4+r)
  float m_[2] = {-1e30f, -1e30f}, l_[2] = {0.f, 0.f};

  const u16* Kg0 = QKV + 2048 + hk * 128;
  const u16* Vg0 = Vt + (size_t)((b * 4 + hk) * 128) * 2048;
  const int r4 = lane >> 4, c16 = lane & 15;

  // staging: tile t of K (rows=key, cols=d) / V (rows=d, cols=key), 8 chunks/wave
  auto stageK = [&](int t) {
    const u16* Kg = Kg0 + (size_t)(b * 2048 + t * 128) * 3072;
    for (int i = 0; i < 8; i++) {
      int grp = i * 4 + wave;
      int row = grp * 4 + r4;
      int ch = c16 ^ (row & 7);
      GLOAD16(Kg + (size_t)row * 3072 + ch * 8, &KP[grp * 512]);
    }
  };
  auto stageV = [&](int t) {
    const u16* Vg = Vg0 + t * 128;
    for (int i = 0; i < 8; i++) {
      int grp = i * 4 + wave;
      int row = grp * 4 + r4;
      int ch = c16 ^ (row & 7);
      GLOAD16(Vg + (size_t)row * 2048 + ch * 8, &Vls[grp * 512]);
    }
  };

  // ---- prologue: stage tile 0 (drained by syncthreads)
  stageK(0);
  stageV(0);
  __syncthreads();

  // bpermute addresses for the P exchange (byte addr = src_lane*4):
  //   srcA = (quad&1)*32 + l16 (even src quad), srcB = srcA + 16 (odd)
  const int bpA = (((quad & 1) << 5) + l16) << 2;
  const int bpB = bpA + 64;
  const bool hi = quad >= 2;  // selects kb = 2ki+1 source values

  for (int kt = 0; kt < 16; kt++) {
    if (kt > 0) stageV(kt);  // in flight until BARRIER_B

    // S^T = K Q^T : A = K-frag (m=key), B = Q-frag (n=q)
    f32x4 s[8][2];
    for (int kb = 0; kb < 8; kb++) {
      bf16x8 kf[4];
      int a0 = (kb * 16 + l16) * 128 + ((quad ^ sw) << 3);
      for (int ki = 0; ki < 4; ki++)
        kf[ki] = *(const bf16x8*)&KP[a0 ^ (ki * 32)];
      __builtin_amdgcn_s_setprio(1);
      for (int qb = 0; qb < 2; qb++) {
        f32x4 a = {0.f, 0.f, 0.f, 0.f};
        for (int ki = 0; ki < 4; ki++)
          a = __builtin_amdgcn_mfma_f32_16x16x32_bf16(kf[ki], qf[qb][ki], a, 0, 0, 0);
        s[kb][qb] = a;
      }
      __builtin_amdgcn_s_setprio(0);
    }

    bar_sync();  // BARRIER_A: all waves' K reads done
    if (kt < 15) stageK(kt + 1);  // in flight until BARRIER_END

    // online softmax per q (q = qb*16 + l16); scores pre-scaled by C*log2e.
    // tree max + defer-max (THR=8 log2); exp fused with bf16 pack into u[8];
    // then cross-quad ds_bpermute exchange -> pf (PV B-fragments, in-reg).
    bf16x8 pf[2][4];
    float alch[2];
    for (int qb = 0; qb < 2; qb++) {
      float mk[8];
#pragma unroll
      for (int kb = 0; kb < 8; kb++)
        mk[kb] = fmaxf(fmaxf(s[kb][qb][0], s[kb][qb][1]),
                       fmaxf(s[kb][qb][2], s[kb][qb][3]));
      float mx = fmaxf(fmaxf(fmaxf(mk[0], mk[1]), fmaxf(mk[2], mk[3])),
                       fmaxf(fmaxf(mk[4], mk[5]), fmaxf(mk[6], mk[7])));
      mx = fmaxf(mx, __shfl_xor(mx, 16, 64));
      mx = fmaxf(mx, __shfl_xor(mx, 32, 64));
      float mn = m_[qb], al = 1.0f;
      if (!__all(mx <= m_[qb] + 8.0f)) {
        mn = fmaxf(m_[qb], mx);
        al = exp2f(m_[qb] - mn);
        m_[qb] = mn;
      }
      alch[qb] = al;
      uint2 u[8];
      float rs = 0.f;
#pragma unroll
      for (int kb = 0; kb < 8; kb++) {
        float p0 = exp2f(s[kb][qb][0] - mn), p1 = exp2f(s[kb][qb][1] - mn);
        float p2 = exp2f(s[kb][qb][2] - mn), p3 = exp2f(s[kb][qb][3] - mn);
        u[kb] = pack4(p0, p1, p2, p3);
        rs += (p0 + p1) + (p2 + p3);
      }
      rs += __shfl_xor(rs, 16, 64);
      rs += __shfl_xor(rs, 32, 64);
      l_[qb] = l_[qb] * al + rs;
      // exchange: pf[qb][ki] = P[q=l16-row][keys ki*32 + quad*8 + 0..7]
      //   dw0/dw1 from srcA (even quad), dw2/dw3 from srcB (odd quad);
      //   value u[2ki] for dst quads 0,1 and u[2ki+1] for quads 2,3.
#pragma unroll
      for (int ki = 0; ki < 4; ki++) {
        int Ax = (int)u[2 * ki].x, Ay = (int)u[2 * ki].y;
        int Bx = (int)u[2 * ki + 1].x, By = (int)u[2 * ki + 1].y;
        int pAx = __builtin_amdgcn_ds_bpermute(bpA, Ax);
        int pBx = __builtin_amdgcn_ds_bpermute(bpA, Bx);
        int pAy = __builtin_amdgcn_ds_bpermute(bpA, Ay);
        int pBy = __builtin_amdgcn_ds_bpermute(bpA, By);
        int qAx = __builtin_amdgcn_ds_bpermute(bpB, Ax);
        int qBx = __builtin_amdgcn_ds_bpermute(bpB, Bx);
        int qAy = __builtin_amdgcn_ds_bpermute(bpB, Ay);
        int qBy = __builtin_amdgcn_ds_bpermute(bpB, By);
        uint4 d;
        d.x = hi ? (uint32_t)pBx : (uint32_t)pAx;
        d.y = hi ? (uint32_t)pBy : (uint32_t)pAy;
        d.z = hi ? (uint32_t)qBx : (uint32_t)qAx;
        d.w = hi ? (uint32_t)qBy : (uint32_t)qAy;
        pf[qb][ki] = *(bf16x8*)&d;
      }
    }
    // O-rescale (only when some row deferred past THR)
    if (alch[0] != 1.0f || alch[1] != 1.0f) {
#pragma unroll
      for (int db = 0; db < 8; db++) {
        o[db][0] *= alch[0];
        o[db][1] *= alch[1];
      }
    }

    // BARRIER_B: drain V_kt (8 older loads; the 8 K_{kt+1} stay flying)
    if (kt == 15) asm volatile("s_waitcnt vmcnt(0)" ::: "memory");
    else          asm volatile("s_waitcnt vmcnt(8)" ::: "memory");
    bar_sync();

    // O^T += V^T P^T : A = V-frag (m=d), B = pf (n=q, in registers)
    for (int db = 0; db < 8; db++) {
      bf16x8 vf[4];
      int a0 = (db * 16 + l16) * 128 + ((quad ^ sw) << 3);
      for (int ki = 0; ki < 4; ki++)
        vf[ki] = *(const bf16x8*)&Vls[a0 ^ (ki * 32)];
      __builtin_amdgcn_s_setprio(1);
      for (int qb = 0; qb < 2; qb++)
        for (int ki = 0; ki < 4; ki++)
          o[db][qb] = __builtin_amdgcn_mfma_f32_16x16x32_bf16(vf[ki], pf[qb][ki], o[db][qb], 0, 0, 0);
      __builtin_amdgcn_s_setprio(0);
    }

    // BARRIER_END: K_{kt+1} landed (covered by softmax+PV); Vls free after
    asm volatile("s_waitcnt vmcnt(0)" ::: "memory");
    bar_sync();
  }

  // epilogue: O^T/l -> LDS [q][d] packed b64 -> coalesced global store
  float inv[2] = {1.0f / l_[0], 1.0f / l_[1]};
  for (int qb = 0; qb < 2; qb++) {
    int rq = wave * 32 + qb * 16 + l16;
    for (int db = 0; db < 8; db++) {
      int ch = (db * 2 + (quad >> 1)) ^ sw;
      uint2 pv = pack4(o[db][qb][0] * inv[qb], o[db][qb][1] * inv[qb],
                       o[db][qb][2] * inv[qb], o[db][qb][3] * inv[qb]);
      *(uint2*)&KP[rq * 128 + (ch << 3) + (quad & 1) * 4] = pv;
    }
  }
  __syncthreads();
  u16* Ab = AO + (size_t)(b * 2048 + qt * 128) * 2048 + h * 128;
  for (int i = 0; i < 8; i++) {
    int row = i * 16 + (tid >> 4);
    int seg = tid & 15;
    int pc = seg ^ (row & 7);
    *(uint4*)(Ab + (size_t)row * 2048 + seg * 8) = *(const uint4*)&KP[row * 128 + pc * 8];
  }
}

// ---------------- launch ----------------
extern "C" void kernel_launch(void* const* d_in, const int* in_sizes, int n_in,
                              void* d_out, int out_size, void* d_ws, size_t ws_size,
                              hipStream_t stream) {
  (void)in_sizes; (void)n_in; (void)out_size; (void)ws_size;
  const float* x    = (const float*)d_in[0];
  const float* fcos = (const float*)d_in[1];
  const float* fsin = (const float*)d_in[2];
  const float* wq   = (const float*)d_in[3];
  const float* wk   = (const float*)d_in[4];
  const float* wv   = (const float*)d_in[5];
  const float* wo   = (const float*)d_in[6];

  char* w = (char*)d_ws;
  u16* xb  = (u16*)w;                               // 8192x2048 bf16, reused as attn_out
  u16* wT  = (u16*)(w + 33554432);                  // 3072x2048 bf16
  u16* woT = (u16*)(w + 33554432 + 12582912);       // 2048x2048 bf16
  u16* QKV = (u16*)(w + 33554432 + 12582912 + 8388608);            // 8192x3072 bf16
  u16* Vt  = (u16*)(w + 33554432 + 12582912 + 8388608 + 50331648); // 16x128x2048 bf16
  u16* AO  = xb;

  const float C = 0.08838834764831845f * 1.44269504088896340f;  // 1/sqrt(128)*log2(e)

  cast_x_kernel<<<16384, 256, 0, stream>>>((const float4*)x, (ushort4*)xb);
  wtrans_kernel<<<dim3(64, 64), dim3(32, 8), 0, stream>>>(wq, wT, 2048, 2048, C);
  wtrans_kernel<<<dim3(16, 64), dim3(32, 8), 0, stream>>>(wk, wT + (size_t)2048 * 2048, 2048, 512, 1.0f);
  wtrans_kernel<<<dim3(16, 64), dim3(32, 8), 0, stream>>>(wv, wT + (size_t)2560 * 2048, 2048, 512, 1.0f);
  wtrans_kernel<<<dim3(64, 64), dim3(32, 8), 0, stream>>>(wo, woT, 2048, 2048, 1.0f);

  gemm_bt_kernel<true><<<dim3(24, 64), 256, 0, stream>>>(xb, wT, QKV, 2048, 3072);
  rope_kernel<<<40960, 256, 0, stream>>>(QKV, fcos, fsin);
  vtrans_kernel<<<dim3(64, 4, 16), dim3(32, 8), 0, stream>>>(QKV, Vt);
  attn_kernel<<<dim3(16, 16, 4), 256, 0, stream>>>(QKV, Vt, AO);
  gemm_bt_kernel<false><<<dim3(16, 64), 256, 0, stream>>>(AO, woT, (float*)d_out, 2048, 2048);
}

// Round 6
// 575.719 us; speedup vs baseline: 1.3101x; 1.0737x over previous
//
#include <hip/hip_runtime.h>
#include <stdint.h>

// Attention_48945447306134 on MI355X.
//   GEMM1: QKV = xb @ [wq*C|wk|wv]^T  (wq pre-scaled by softmax_scale*log2e)
//   RoPE in place; V pre-transposed to Vt[b][hk][d][s]
//   Flash attention, TRANSPOSED algebra: S^T = K Q^T, O^T = V^T P^T
//   This rev: (a) GEMM K-step 32->64 (halves barrier drains; XOR chunk
//   swizzle keeps ds_read_b128 at the 8-lane/bank-group minimum);
//   (b) attn P-exchange via permlane32_swap + xor16 swizzle (replaces 8
//   ds_bpermute with 2 VALU permlane + 4 swizzle + 4 cndmask per ki).
//   Keeps: in-reg P, K/V staging fully covered by counted vmcnt, defer-max,
//   cvt_pk packing, tree reductions, setprio.
//   GEMM2: out = attn @ woT (fp32 out)

typedef unsigned short u16;
typedef __bf16 bf16x8 __attribute__((ext_vector_type(8)));
typedef float  f32x4  __attribute__((ext_vector_type(4)));
typedef unsigned int u32x2 __attribute__((ext_vector_type(2)));

#define GLOAD16(gp, lp)                                                        \
  __builtin_amdgcn_global_load_lds(                                            \
      (const __attribute__((address_space(1))) void*)(gp),                     \
      (__attribute__((address_space(3))) void*)(lp), 16, 0, 0)

__device__ __forceinline__ u16 f2b(float f) {  // RNE f32->bf16
  union { float f; uint32_t u; } v; v.f = f;
  uint32_t r = v.u + 0x7FFFu + ((v.u >> 16) & 1u);
  return (u16)(r >> 16);
}
__device__ __forceinline__ float b2f(u16 h) {
  union { uint32_t u; float f; } v; v.u = ((uint32_t)h) << 16;
  return v.f;
}
// RNE pack via HW instruction
__device__ __forceinline__ uint2 pack4(float a, float b, float c, float d) {
  uint2 r;
  asm("v_cvt_pk_bf16_f32 %0, %1, %2" : "=v"(r.x) : "v"(a), "v"(b));
  asm("v_cvt_pk_bf16_f32 %0, %1, %2" : "=v"(r.y) : "v"(c), "v"(d));
  return r;
}

// block barrier that does NOT drain vmcnt (keeps staging loads in flight).
__device__ __forceinline__ void bar_sync() {
  asm volatile("s_waitcnt lgkmcnt(0)" ::: "memory");
  __builtin_amdgcn_s_barrier();
  asm volatile("" ::: "memory");
}

// ---------------- cast x -> bf16 ----------------
__global__ __launch_bounds__(256) void cast_x_kernel(const float4* __restrict__ in,
                                                     ushort4* __restrict__ out) {
  int i = blockIdx.x * 256 + threadIdx.x;
  float4 v = in[i];
  ushort4 o;
  o.x = f2b(v.x); o.y = f2b(v.y); o.z = f2b(v.z); o.w = f2b(v.w);
  out[i] = o;
}

// ------------- cast + transpose weight: W (KxN f32) -> WT (NxK bf16), * scale -------------
__global__ __launch_bounds__(256) void wtrans_kernel(const float* __restrict__ W,
                                                     u16* __restrict__ WT,
                                                     int K, int N, float scale) {
  __shared__ float t[32][33];
  int n0 = blockIdx.x * 32, k0 = blockIdx.y * 32;
  int tx = threadIdx.x, ty = threadIdx.y;  // 32 x 8
  for (int r = 0; r < 4; r++)
    t[ty + r * 8][tx] = W[(size_t)(k0 + ty + r * 8) * N + n0 + tx];
  __syncthreads();
  for (int r = 0; r < 4; r++)
    WT[(size_t)(n0 + ty + r * 8) * K + k0 + tx] = f2b(t[tx][ty + r * 8] * scale);
}

// ---------------- GEMM: C(MxN) = A(MxK) * BT(NxK)^T, BK=64 + swizzle ----------------
// LDS [128][64] u16 per matrix (32KB total). Stage: 4 gload16/matrix/K-step;
// lane l of instr c covers row = c*32 + wave*8 + (l>>3), stored chunk l&7 =
// true chunk (l&7)^(row&7). Read: stored chunk (4*kk+quad)^(row&7) recovers
// true col kk*32+quad*8. Keeps ds_read_b128 conflict at the 8-lane/group min.
template <bool BF16OUT>
__global__ __launch_bounds__(256) void gemm_bt_kernel(const u16* __restrict__ A,
                                                      const u16* __restrict__ BT,
                                                      void* __restrict__ Cv,
                                                      int K, int N) {
  __shared__ u16 As[128 * 64];
  __shared__ u16 Bs[128 * 64];
  const int tid = threadIdx.x;
  const int wave = tid >> 6, lane = tid & 63;
  const int quad = lane >> 4, l16 = lane & 15;
  const int wm = (wave >> 1) * 64, wn = (wave & 1) * 64;
  const size_t m0 = (size_t)blockIdx.y * 128, n0 = (size_t)blockIdx.x * 128;

  f32x4 acc[4][4] = {};
  const int srow = lane >> 3;                 // 0..7 within the 8-row group
  const int scol = ((lane & 7) ^ srow) * 8;   // pre-swizzled global chunk
  const u16* Ag = A + (m0 + wave * 8 + srow) * (size_t)K + scol;
  const u16* Bg = BT + (n0 + wave * 8 + srow) * (size_t)K + scol;
  const int sw7 = l16 & 7;

  for (int k0 = 0; k0 < K; k0 += 64) {
    for (int c = 0; c < 4; c++) {
      GLOAD16(Ag + (size_t)(c * 32) * K + k0, &As[(c * 32 + wave * 8) * 64]);
      GLOAD16(Bg + (size_t)(c * 32) * K + k0, &Bs[(c * 32 + wave * 8) * 64]);
    }
    __syncthreads();
    for (int kk = 0; kk < 2; kk++) {
      bf16x8 af[4], bf[4];
      const int ch = ((4 * kk + quad) ^ sw7) << 3;
      for (int i = 0; i < 4; i++)
        af[i] = *(const bf16x8*)&As[(wm + i * 16 + l16) * 64 + ch];
      for (int i = 0; i < 4; i++)
        bf[i] = *(const bf16x8*)&Bs[(wn + i * 16 + l16) * 64 + ch];
      for (int mi = 0; mi < 4; mi++)
        for (int ni = 0; ni < 4; ni++)
          acc[mi][ni] = __builtin_amdgcn_mfma_f32_16x16x32_bf16(af[mi], bf[ni], acc[mi][ni], 0, 0, 0);
    }
    __syncthreads();
  }
  for (int mi = 0; mi < 4; mi++)
    for (int ni = 0; ni < 4; ni++)
      for (int r = 0; r < 4; r++) {
        size_t row = m0 + wm + mi * 16 + quad * 4 + r;
        size_t col = n0 + wn + ni * 16 + l16;
        if (BF16OUT) ((u16*)Cv)[row * N + col] = f2b(acc[mi][ni][r]);
        else         ((float*)Cv)[row * N + col] = acc[mi][ni][r];
      }
}

// ---------------- RoPE in place on QKV cols [0,2560) ----------------
__global__ __launch_bounds__(256) void rope_kernel(u16* __restrict__ QKV,
                                                   const float* __restrict__ cs,
                                                   const float* __restrict__ sn) {
  int tid = blockIdx.x * 256 + threadIdx.x;
  int row = tid / 1280;
  int p = tid - row * 1280;
  int s = row & 2047;
  int head = p >> 6, i = p & 63;
  u16* ptr = QKV + (size_t)row * 3072 + head * 128 + i * 2;
  unsigned int v = *(unsigned int*)ptr;
  float x0 = b2f((u16)(v & 0xffff)), x1 = b2f((u16)(v >> 16));
  float c = cs[s * 64 + i], ss = sn[s * 64 + i];
  u16 o0 = f2b(x0 * c - x1 * ss);
  u16 o1 = f2b(x0 * ss + x1 * c);
  *(unsigned int*)ptr = (unsigned int)o0 | ((unsigned int)o1 << 16);
}

// ---------------- V transpose ----------------
__global__ __launch_bounds__(256) void vtrans_kernel(const u16* __restrict__ QKV,
                                                     u16* __restrict__ Vt) {
  __shared__ u16 t[32][33];
  int b = blockIdx.z >> 2, hk = blockIdx.z & 3;
  int s0 = blockIdx.x * 32, d0 = blockIdx.y * 32;
  int tx = threadIdx.x, ty = threadIdx.y;
  const u16* src = QKV + (size_t)(b * 2048 + s0) * 3072 + 2560 + hk * 128 + d0;
  for (int r = 0; r < 4; r++)
    t[ty + r * 8][tx] = src[(size_t)(ty + r * 8) * 3072 + tx];
  __syncthreads();
  u16* dst = Vt + ((size_t)((b * 4 + hk) * 128 + d0)) * 2048 + s0;
  for (int r = 0; r < 4; r++)
    dst[(size_t)(ty + r * 8) * 2048 + tx] = t[tx][ty + r * 8];
}

// ---------------- flash attention (transposed algebra, P in registers) ------
// grid (qt=16, h=16, b=4), 256 threads = 4 waves, 32 q-rows/wave.
// Per iter kt:
//   [top] if kt>0: issue V_kt gload_lds
//   QK^T -> BARRIER_A -> issue K_{kt+1} gload_lds
//   softmax + exp->bf16 pack -> permlane32_swap/xor16 exchange -> pf (in-reg)
//   BARRIER_B: vmcnt(8) (drain V_kt, keep K flying)
//   PV -> BARRIER_END: vmcnt(0)
__global__ __launch_bounds__(256, 2) void attn_kernel(const u16* __restrict__ QKV,
                                                      const u16* __restrict__ Vt,
                                                      u16* __restrict__ AO) {
  __shared__ u16 KP[128 * 128];
  __shared__ u16 Vls[128 * 128];
  const int tid = threadIdx.x;
  const int wave = tid >> 6, lane = tid & 63;
  const int quad = lane >> 4, l16 = lane & 15;
  const int qt = blockIdx.x, h = blockIdx.y, b = blockIdx.z;
  const int hk = h >> 2;
  const int sw = l16 & 7;  // row-dependent swizzle key for this lane's rows

  // Q fragments (B-operand: n=q=l16, k=d)
  bf16x8 qf[2][4];
  {
    const u16* Qb = QKV + (size_t)(b * 2048 + qt * 128 + wave * 32) * 3072 + h * 128;
    for (int qb = 0; qb < 2; qb++)
      for (int ki = 0; ki < 4; ki++)
        qf[qb][ki] = *(const bf16x8*)(Qb + (size_t)(qb * 16 + l16) * 3072 + ki * 32 + quad * 8);
  }
  f32x4 o[8][2] = {};            // O^T: [db][qb], col=q(l16), row=d(quad*4+r)
  float m_[2] = {-1e30f, -1e30f}, l_[2] = {0.f, 0.f};

  const u16* Kg0 = QKV + 2048 + hk * 128;
  const u16* Vg0 = Vt + (size_t)((b * 4 + hk) * 128) * 2048;
  const int r4 = lane >> 4, c16 = lane & 15;

  // staging: tile t of K (rows=key, cols=d) / V (rows=d, cols=key), 8 chunks/wave
  auto stageK = [&](int t) {
    const u16* Kg = Kg0 + (size_t)(b * 2048 + t * 128) * 3072;
    for (int i = 0; i < 8; i++) {
      int grp = i * 4 + wave;
      int row = grp * 4 + r4;
      int ch = c16 ^ (row & 7);
      GLOAD16(Kg + (size_t)row * 3072 + ch * 8, &KP[grp * 512]);
    }
  };
  auto stageV = [&](int t) {
    const u16* Vg = Vg0 + t * 128;
    for (int i = 0; i < 8; i++) {
      int grp = i * 4 + wave;
      int row = grp * 4 + r4;
      int ch = c16 ^ (row & 7);
      GLOAD16(Vg + (size_t)row * 2048 + ch * 8, &Vls[grp * 512]);
    }
  };

  // ---- prologue: stage tile 0 (drained by syncthreads)
  stageK(0);
  stageV(0);
  __syncthreads();

  for (int kt = 0; kt < 16; kt++) {
    if (kt > 0) stageV(kt);  // in flight until BARRIER_B

    // S^T = K Q^T : A = K-frag (m=key), B = Q-frag (n=q)
    f32x4 s[8][2];
    for (int kb = 0; kb < 8; kb++) {
      bf16x8 kf[4];
      int a0 = (kb * 16 + l16) * 128 + ((quad ^ sw) << 3);
      for (int ki = 0; ki < 4; ki++)
        kf[ki] = *(const bf16x8*)&KP[a0 ^ (ki * 32)];
      __builtin_amdgcn_s_setprio(1);
      for (int qb = 0; qb < 2; qb++) {
        f32x4 a = {0.f, 0.f, 0.f, 0.f};
        for (int ki = 0; ki < 4; ki++)
          a = __builtin_amdgcn_mfma_f32_16x16x32_bf16(kf[ki], qf[qb][ki], a, 0, 0, 0);
        s[kb][qb] = a;
      }
      __builtin_amdgcn_s_setprio(0);
    }

    bar_sync();  // BARRIER_A: all waves' K reads done
    if (kt < 15) stageK(kt + 1);  // in flight until BARRIER_END

    // online softmax per q (q = qb*16 + l16); scores pre-scaled by C*log2e.
    // tree max + defer-max (THR=8 log2); exp fused with bf16 pack into u[8];
    // then permlane32_swap + xor16 exchange -> pf (PV B-fragments, in-reg).
    bf16x8 pf[2][4];
    float alch[2];
    for (int qb = 0; qb < 2; qb++) {
      float mk[8];
#pragma unroll
      for (int kb = 0; kb < 8; kb++)
        mk[kb] = fmaxf(fmaxf(s[kb][qb][0], s[kb][qb][1]),
                       fmaxf(s[kb][qb][2], s[kb][qb][3]));
      float mx = fmaxf(fmaxf(fmaxf(mk[0], mk[1]), fmaxf(mk[2], mk[3])),
                       fmaxf(fmaxf(mk[4], mk[5]), fmaxf(mk[6], mk[7])));
      mx = fmaxf(mx, __shfl_xor(mx, 16, 64));
      mx = fmaxf(mx, __shfl_xor(mx, 32, 64));
      float mn = m_[qb], al = 1.0f;
      if (!__all(mx <= m_[qb] + 8.0f)) {
        mn = fmaxf(m_[qb], mx);
        al = exp2f(m_[qb] - mn);
        m_[qb] = mn;
      }
      alch[qb] = al;
      uint2 u[8];
      float rs = 0.f;
#pragma unroll
      for (int kb = 0; kb < 8; kb++) {
        float p0 = exp2f(s[kb][qb][0] - mn), p1 = exp2f(s[kb][qb][1] - mn);
        float p2 = exp2f(s[kb][qb][2] - mn), p3 = exp2f(s[kb][qb][3] - mn);
        u[kb] = pack4(p0, p1, p2, p3);
        rs += (p0 + p1) + (p2 + p3);
      }
      rs += __shfl_xor(rs, 16, 64);
      rs += __shfl_xor(rs, 32, 64);
      l_[qb] = l_[qb] * al + rs;
      // exchange: pf[qb][ki] = P[q=l16-row][keys ki*32 + quad*8 + 0..7].
      // permlane32_swap(a,b): a' = [a_lo, b_lo], b' = [a_hi, b_hi].
      // d.x = odd(quad) ? xor16(b') : a'   (A=u[2ki].x, B=u[2ki+1].x)
      // d.z = odd(quad) ? b' : xor16(a')
      // (verified lane-by-lane at lanes 1, 17, 33, 49 vs the bpermute map)
      const bool qo = (quad & 1) != 0;
#pragma unroll
      for (int ki = 0; ki < 4; ki++) {
        u32x2 r1 = __builtin_amdgcn_permlane32_swap(u[2 * ki].x, u[2 * ki + 1].x, false, false);
        u32x2 r2 = __builtin_amdgcn_permlane32_swap(u[2 * ki].y, u[2 * ki + 1].y, false, false);
        uint32_t t1b = (uint32_t)__shfl_xor((int)r1[1], 16, 64);
        uint32_t t1a = (uint32_t)__shfl_xor((int)r1[0], 16, 64);
        uint32_t t2b = (uint32_t)__shfl_xor((int)r2[1], 16, 64);
        uint32_t t2a = (uint32_t)__shfl_xor((int)r2[0], 16, 64);
        uint4 d;
        d.x = qo ? t1b : (uint32_t)r1[0];
        d.y = qo ? t2b : (uint32_t)r2[0];
        d.z = qo ? (uint32_t)r1[1] : t1a;
        d.w = qo ? (uint32_t)r2[1] : t2a;
        pf[qb][ki] = *(bf16x8*)&d;
      }
    }
    // O-rescale (only when some row deferred past THR)
    if (alch[0] != 1.0f || alch[1] != 1.0f) {
#pragma unroll
      for (int db = 0; db < 8; db++) {
        o[db][0] *= alch[0];
        o[db][1] *= alch[1];
      }
    }

    // BARRIER_B: drain V_kt (8 older loads; the 8 K_{kt+1} stay flying)
    if (kt == 15) asm volatile("s_waitcnt vmcnt(0)" ::: "memory");
    else          asm volatile("s_waitcnt vmcnt(8)" ::: "memory");
    bar_sync();

    // O^T += V^T P^T : A = V-frag (m=d), B = pf (n=q, in registers)
    for (int db = 0; db < 8; db++) {
      bf16x8 vf[4];
      int a0 = (db * 16 + l16) * 128 + ((quad ^ sw) << 3);
      for (int ki = 0; ki < 4; ki++)
        vf[ki] = *(const bf16x8*)&Vls[a0 ^ (ki * 32)];
      __builtin_amdgcn_s_setprio(1);
      for (int qb = 0; qb < 2; qb++)
        for (int ki = 0; ki < 4; ki++)
          o[db][qb] = __builtin_amdgcn_mfma_f32_16x16x32_bf16(vf[ki], pf[qb][ki], o[db][qb], 0, 0, 0);
      __builtin_amdgcn_s_setprio(0);
    }

    // BARRIER_END: K_{kt+1} landed (covered by softmax+PV); Vls free after
    asm volatile("s_waitcnt vmcnt(0)" ::: "memory");
    bar_sync();
  }

  // epilogue: O^T/l -> LDS [q][d] packed b64 -> coalesced global store
  float inv[2] = {1.0f / l_[0], 1.0f / l_[1]};
  for (int qb = 0; qb < 2; qb++) {
    int rq = wave * 32 + qb * 16 + l16;
    for (int db = 0; db < 8; db++) {
      int ch = (db * 2 + (quad >> 1)) ^ sw;
      uint2 pv = pack4(o[db][qb][0] * inv[qb], o[db][qb][1] * inv[qb],
                       o[db][qb][2] * inv[qb], o[db][qb][3] * inv[qb]);
      *(uint2*)&KP[rq * 128 + (ch << 3) + (quad & 1) * 4] = pv;
    }
  }
  __syncthreads();
  u16* Ab = AO + (size_t)(b * 2048 + qt * 128) * 2048 + h * 128;
  for (int i = 0; i < 8; i++) {
    int row = i * 16 + (tid >> 4);
    int seg = tid & 15;
    int pc = seg ^ (row & 7);
    *(uint4*)(Ab + (size_t)row * 2048 + seg * 8) = *(const uint4*)&KP[row * 128 + pc * 8];
  }
}

// ---------------- launch ----------------
extern "C" void kernel_launch(void* const* d_in, const int* in_sizes, int n_in,
                              void* d_out, int out_size, void* d_ws, size_t ws_size,
                              hipStream_t stream) {
  (void)in_sizes; (void)n_in; (void)out_size; (void)ws_size;
  const float* x    = (const float*)d_in[0];
  const float* fcos = (const float*)d_in[1];
  const float* fsin = (const float*)d_in[2];
  const float* wq   = (const float*)d_in[3];
  const float* wk   = (const float*)d_in[4];
  const float* wv   = (const float*)d_in[5];
  const float* wo   = (const float*)d_in[6];

  char* w = (char*)d_ws;
  u16* xb  = (u16*)w;                               // 8192x2048 bf16, reused as attn_out
  u16* wT  = (u16*)(w + 33554432);                  // 3072x2048 bf16
  u16* woT = (u16*)(w + 33554432 + 12582912);       // 2048x2048 bf16
  u16* QKV = (u16*)(w + 33554432 + 12582912 + 8388608);            // 8192x3072 bf16
  u16* Vt  = (u16*)(w + 33554432 + 12582912 + 8388608 + 50331648); // 16x128x2048 bf16
  u16* AO  = xb;

  const float C = 0.08838834764831845f * 1.44269504088896340f;  // 1/sqrt(128)*log2(e)

  cast_x_kernel<<<16384, 256, 0, stream>>>((const float4*)x, (ushort4*)xb);
  wtrans_kernel<<<dim3(64, 64), dim3(32, 8), 0, stream>>>(wq, wT, 2048, 2048, C);
  wtrans_kernel<<<dim3(16, 64), dim3(32, 8), 0, stream>>>(wk, wT + (size_t)2048 * 2048, 2048, 512, 1.0f);
  wtrans_kernel<<<dim3(16, 64), dim3(32, 8), 0, stream>>>(wv, wT + (size_t)2560 * 2048, 2048, 512, 1.0f);
  wtrans_kernel<<<dim3(64, 64), dim3(32, 8), 0, stream>>>(wo, woT, 2048, 2048, 1.0f);

  gemm_bt_kernel<true><<<dim3(24, 64), 256, 0, stream>>>(xb, wT, QKV, 2048, 3072);
  rope_kernel<<<40960, 256, 0, stream>>>(QKV, fcos, fsin);
  vtrans_kernel<<<dim3(64, 4, 16), dim3(32, 8), 0, stream>>>(QKV, Vt);
  attn_kernel<<<dim3(16, 16, 4), 256, 0, stream>>>(QKV, Vt, AO);
  gemm_bt_kernel<false><<<dim3(16, 64), 256, 0, stream>>>(AO, woT, (float*)d_out, 2048, 2048);
}

// Round 8
// 573.066 us; speedup vs baseline: 1.3162x; 1.0046x over previous
//
#include <hip/hip_runtime.h>
#include <stdint.h>

// Attention_48945447306134 on MI355X.
//   GEMM1: QKV = xb @ [wq*C|wk|wv]^T  (wq pre-scaled by softmax_scale*log2e)
//   RoPE in place; V pre-transposed to Vt[b][hk][d][s]
//   Flash attention, TRANSPOSED algebra: S^T = K Q^T, O^T = V^T P^T
//   This rev (resubmit of r7 after container-level infra failure; audited for
//   hang / OOB DMA / layout+pipeline correctness -- all clean):
//   GEMM rebuilt as BK=32 double-buffered pipeline (attn-proven schedule:
//   vmcnt(0)+barrier with full-tile cover, stage-early into the other buffer,
//   setprio around MFMA; paired-row LDS layout keeps ds_read_b128 at the
//   8-lane/bank-group minimum). XCD-aware block swizzle on both GEMMs and
//   attn. attn kernel otherwise unchanged from round 6.
//   GEMM2: out = attn @ woT (fp32 out)

typedef unsigned short u16;
typedef __bf16 bf16x8 __attribute__((ext_vector_type(8)));
typedef float  f32x4  __attribute__((ext_vector_type(4)));
typedef unsigned int u32x2 __attribute__((ext_vector_type(2)));

#define GLOAD16(gp, lp)                                                        \
  __builtin_amdgcn_global_load_lds(                                            \
      (const __attribute__((address_space(1))) void*)(gp),                     \
      (__attribute__((address_space(3))) void*)(lp), 16, 0, 0)

__device__ __forceinline__ u16 f2b(float f) {  // RNE f32->bf16
  union { float f; uint32_t u; } v; v.f = f;
  uint32_t r = v.u + 0x7FFFu + ((v.u >> 16) & 1u);
  return (u16)(r >> 16);
}
__device__ __forceinline__ float b2f(u16 h) {
  union { uint32_t u; float f; } v; v.u = ((uint32_t)h) << 16;
  return v.f;
}
// RNE pack via HW instruction
__device__ __forceinline__ uint2 pack4(float a, float b, float c, float d) {
  uint2 r;
  asm("v_cvt_pk_bf16_f32 %0, %1, %2" : "=v"(r.x) : "v"(a), "v"(b));
  asm("v_cvt_pk_bf16_f32 %0, %1, %2" : "=v"(r.y) : "v"(c), "v"(d));
  return r;
}

// block barrier that does NOT drain vmcnt (keeps staging loads in flight).
__device__ __forceinline__ void bar_sync() {
  asm volatile("s_waitcnt lgkmcnt(0)" ::: "memory");
  __builtin_amdgcn_s_barrier();
  asm volatile("" ::: "memory");
}

// ---------------- cast x -> bf16 ----------------
__global__ __launch_bounds__(256) void cast_x_kernel(const float4* __restrict__ in,
                                                     ushort4* __restrict__ out) {
  int i = blockIdx.x * 256 + threadIdx.x;
  float4 v = in[i];
  ushort4 o;
  o.x = f2b(v.x); o.y = f2b(v.y); o.z = f2b(v.z); o.w = f2b(v.w);
  out[i] = o;
}

// ------------- cast + transpose weight: W (KxN f32) -> WT (NxK bf16), * scale -------------
__global__ __launch_bounds__(256) void wtrans_kernel(const float* __restrict__ W,
                                                     u16* __restrict__ WT,
                                                     int K, int N, float scale) {
  __shared__ float t[32][33];
  int n0 = blockIdx.x * 32, k0 = blockIdx.y * 32;
  int tx = threadIdx.x, ty = threadIdx.y;  // 32 x 8
  for (int r = 0; r < 4; r++)
    t[ty + r * 8][tx] = W[(size_t)(k0 + ty + r * 8) * N + n0 + tx];
  __syncthreads();
  for (int r = 0; r < 4; r++)
    WT[(size_t)(n0 + ty + r * 8) * K + k0 + tx] = f2b(t[tx][ty + r * 8] * scale);
}

// ---------------- GEMM: C(MxN) = A(MxK) * BT(NxK)^T ----------------
// 128x128 tile, BK=32, double-buffered LDS (32 KB total), 1 barrier +
// covered vmcnt(0) per K-tile.  LDS layout: paired rows -- logical row r,
// 16B-chunk q stored at line r>>1, sub r&1, chunk q ^ ((r>>1)&3):
//   u16 idx = (r>>1)*64 + (r&1)*32 + (q^((r>>1)&3))*8.
// Staging (per wave, 2 instrs/matrix of 16 rows each): lane ->
//   row = base + (lane>>3)*2 + ((lane>>2)&1), true chunk = (lane&3)^((lane>>3)&3)
// which makes the linear gload_lds dest land exactly on this layout.
// Frag read: 8 distinct 16B bank-groups per 8 consecutive l16 -> b128 minimum.
#define KSTEP(CUR, NXT, TT)                                                    \
  {                                                                            \
    asm volatile("s_waitcnt vmcnt(0)" ::: "memory");                           \
    bar_sync();                                                                \
    if ((TT) + 1 < nt) {                                                       \
      const size_t k0 = (size_t)((TT) + 1) * 32;                               \
      GLOAD16(Ag + k0, &As[NXT][ldst]);                                        \
      GLOAD16(Ag + k0 + (size_t)16 * K, &As[NXT][ldst + 512]);                 \
      GLOAD16(Bg + k0, &Bs[NXT][ldst]);                                        \
      GLOAD16(Bg + k0 + (size_t)16 * K, &Bs[NXT][ldst + 512]);                 \
    }                                                                          \
    bf16x8 af[4], bf[4];                                                       \
    for (int i = 0; i < 4; i++)                                                \
      af[i] = *(const bf16x8*)&As[CUR][wm * 32 + i * 512 + lrd];               \
    for (int i = 0; i < 4; i++)                                                \
      bf[i] = *(const bf16x8*)&Bs[CUR][wn * 32 + i * 512 + lrd];               \
    __builtin_amdgcn_s_setprio(1);                                             \
    for (int mi = 0; mi < 4; mi++)                                             \
      for (int ni = 0; ni < 4; ni++)                                           \
        acc[mi][ni] = __builtin_amdgcn_mfma_f32_16x16x32_bf16(                 \
            af[mi], bf[ni], acc[mi][ni], 0, 0, 0);                             \
    __builtin_amdgcn_s_setprio(0);                                             \
  }

template <bool BF16OUT>
__global__ __launch_bounds__(256) void gemm_bt_kernel(const u16* __restrict__ A,
                                                      const u16* __restrict__ BT,
                                                      void* __restrict__ Cv,
                                                      int K, int N) {
  __shared__ u16 As[2][64 * 64];
  __shared__ u16 Bs[2][64 * 64];
  const int tid = threadIdx.x;
  const int wave = tid >> 6, lane = tid & 63;
  const int quad = lane >> 4, l16 = lane & 15;
  const int wm = (wave >> 1) * 64, wn = (wave & 1) * 64;

  // XCD-aware bijective block swizzle (nwg % 8 == 0 for both call sites)
  const int nbx = gridDim.x;
  const int nwg = nbx * gridDim.y;
  const int d = blockIdx.x + blockIdx.y * nbx;
  const int w = (d & 7) * (nwg >> 3) + (d >> 3);
  const size_t m0 = (size_t)(w / nbx) * 128, n0 = (size_t)(w % nbx) * 128;

  f32x4 acc[4][4] = {};
  const int srow = wave * 32 + ((lane >> 3) << 1) + ((lane >> 2) & 1);
  const int tcol = ((lane & 3) ^ ((lane >> 3) & 3)) * 8;
  const u16* Ag = A + (m0 + srow) * (size_t)K + tcol;
  const u16* Bg = BT + (n0 + srow) * (size_t)K + tcol;
  const int ldst = wave * 1024;  // u16; per-instr +512 (16 rows)
  const int lrd = (l16 >> 1) * 64 + (l16 & 1) * 32 +
                  ((quad ^ ((l16 >> 1) & 3)) << 3);
  const int nt = K >> 5;

  // prologue: stage tile 0 into buffer 0
  GLOAD16(Ag, &As[0][ldst]);
  GLOAD16(Ag + (size_t)16 * K, &As[0][ldst + 512]);
  GLOAD16(Bg, &Bs[0][ldst]);
  GLOAD16(Bg + (size_t)16 * K, &Bs[0][ldst + 512]);

  for (int t = 0; t < nt; t += 2) {
    KSTEP(0, 1, t);
    KSTEP(1, 0, t + 1);
  }

  for (int mi = 0; mi < 4; mi++)
    for (int ni = 0; ni < 4; ni++)
      for (int r = 0; r < 4; r++) {
        size_t row = m0 + wm + mi * 16 + quad * 4 + r;
        size_t col = n0 + wn + ni * 16 + l16;
        if (BF16OUT) ((u16*)Cv)[row * N + col] = f2b(acc[mi][ni][r]);
        else         ((float*)Cv)[row * N + col] = acc[mi][ni][r];
      }
}

// ---------------- RoPE in place on QKV cols [0,2560) ----------------
__global__ __launch_bounds__(256) void rope_kernel(u16* __restrict__ QKV,
                                                   const float* __restrict__ cs,
                                                   const float* __restrict__ sn) {
  int tid = blockIdx.x * 256 + threadIdx.x;
  int row = tid / 1280;
  int p = tid - row * 1280;
  int s = row & 2047;
  int head = p >> 6, i = p & 63;
  u16* ptr = QKV + (size_t)row * 3072 + head * 128 + i * 2;
  unsigned int v = *(unsigned int*)ptr;
  float x0 = b2f((u16)(v & 0xffff)), x1 = b2f((u16)(v >> 16));
  float c = cs[s * 64 + i], ss = sn[s * 64 + i];
  u16 o0 = f2b(x0 * c - x1 * ss);
  u16 o1 = f2b(x0 * ss + x1 * c);
  *(unsigned int*)ptr = (unsigned int)o0 | ((unsigned int)o1 << 16);
}

// ---------------- V transpose ----------------
__global__ __launch_bounds__(256) void vtrans_kernel(const u16* __restrict__ QKV,
                                                     u16* __restrict__ Vt) {
  __shared__ u16 t[32][33];
  int b = blockIdx.z >> 2, hk = blockIdx.z & 3;
  int s0 = blockIdx.x * 32, d0 = blockIdx.y * 32;
  int tx = threadIdx.x, ty = threadIdx.y;
  const u16* src = QKV + (size_t)(b * 2048 + s0) * 3072 + 2560 + hk * 128 + d0;
  for (int r = 0; r < 4; r++)
    t[ty + r * 8][tx] = src[(size_t)(ty + r * 8) * 3072 + tx];
  __syncthreads();
  u16* dst = Vt + ((size_t)((b * 4 + hk) * 128 + d0)) * 2048 + s0;
  for (int r = 0; r < 4; r++)
    dst[(size_t)(ty + r * 8) * 2048 + tx] = t[tx][ty + r * 8];
}

// ---------------- flash attention (transposed algebra, P in registers) ------
// grid 1024 blocks (XCD-swizzled (qt,h,b)), 256 threads = 4 waves.
// Per iter kt:
//   [top] if kt>0: issue V_kt gload_lds
//   QK^T -> BARRIER_A -> issue K_{kt+1} gload_lds
//   softmax + exp->bf16 pack -> permlane32_swap/xor16 exchange -> pf (in-reg)
//   BARRIER_B: vmcnt(8) (drain V_kt, keep K flying)
//   PV -> BARRIER_END: vmcnt(0)
__global__ __launch_bounds__(256, 2) void attn_kernel(const u16* __restrict__ QKV,
                                                      const u16* __restrict__ Vt,
                                                      u16* __restrict__ AO) {
  __shared__ u16 KP[128 * 128];
  __shared__ u16 Vls[128 * 128];
  const int tid = threadIdx.x;
  const int wave = tid >> 6, lane = tid & 63;
  const int quad = lane >> 4, l16 = lane & 15;
  // XCD-aware bijective swizzle: co-locate the 16 qt-blocks sharing each
  // (h,b) K/V set on one XCD (1024 blocks, 8 XCDs -> 128 per XCD).
  const int d0s = blockIdx.x + 16 * (blockIdx.y + 16 * blockIdx.z);
  const int w0 = (d0s & 7) * 128 + (d0s >> 3);
  const int qt = w0 & 15, h = (w0 >> 4) & 15, b = w0 >> 8;
  const int hk = h >> 2;
  const int sw = l16 & 7;  // row-dependent swizzle key for this lane's rows

  // Q fragments (B-operand: n=q=l16, k=d)
  bf16x8 qf[2][4];
  {
    const u16* Qb = QKV + (size_t)(b * 2048 + qt * 128 + wave * 32) * 3072 + h * 128;
    for (int qb = 0; qb < 2; qb++)
      for (int ki = 0; ki < 4; ki++)
        qf[qb][ki] = *(const bf16x8*)(Qb + (size_t)(qb * 16 + l16) * 3072 + ki * 32 + quad * 8);
  }
  f32x4 o[8][2] = {};            // O^T: [db][qb], col=q(l16), row=d(quad*4+r)
  float m_[2] = {-1e30f, -1e30f}, l_[2] = {0.f, 0.f};

  const u16* Kg0 = QKV + 2048 + hk * 128;
  const u16* Vg0 = Vt + (size_t)((b * 4 + hk) * 128) * 2048;
  const int r4 = lane >> 4, c16 = lane & 15;

  // staging: tile t of K (rows=key, cols=d) / V (rows=d, cols=key), 8 chunks/wave
  auto stageK = [&](int t) {
    const u16* Kg = Kg0 + (size_t)(b * 2048 + t * 128) * 3072;
    for (int i = 0; i < 8; i++) {
      int grp = i * 4 + wave;
      int row = grp * 4 + r4;
      int ch = c16 ^ (row & 7);
      GLOAD16(Kg + (size_t)row * 3072 + ch * 8, &KP[grp * 512]);
    }
  };
  auto stageV = [&](int t) {
    const u16* Vg = Vg0 + t * 128;
    for (int i = 0; i < 8; i++) {
      int grp = i * 4 + wave;
      int row = grp * 4 + r4;
      int ch = c16 ^ (row & 7);
      GLOAD16(Vg + (size_t)row * 2048 + ch * 8, &Vls[grp * 512]);
    }
  };

  // ---- prologue: stage tile 0 (drained by syncthreads)
  stageK(0);
  stageV(0);
  __syncthreads();

  for (int kt = 0; kt < 16; kt++) {
    if (kt > 0) stageV(kt);  // in flight until BARRIER_B

    // S^T = K Q^T : A = K-frag (m=key), B = Q-frag (n=q)
    f32x4 s[8][2];
    for (int kb = 0; kb < 8; kb++) {
      bf16x8 kf[4];
      int a0 = (kb * 16 + l16) * 128 + ((quad ^ sw) << 3);
      for (int ki = 0; ki < 4; ki++)
        kf[ki] = *(const bf16x8*)&KP[a0 ^ (ki * 32)];
      __builtin_amdgcn_s_setprio(1);
      for (int qb = 0; qb < 2; qb++) {
        f32x4 a = {0.f, 0.f, 0.f, 0.f};
        for (int ki = 0; ki < 4; ki++)
          a = __builtin_amdgcn_mfma_f32_16x16x32_bf16(kf[ki], qf[qb][ki], a, 0, 0, 0);
        s[kb][qb] = a;
      }
      __builtin_amdgcn_s_setprio(0);
    }

    bar_sync();  // BARRIER_A: all waves' K reads done
    if (kt < 15) stageK(kt + 1);  // in flight until BARRIER_END

    // online softmax per q (q = qb*16 + l16); scores pre-scaled by C*log2e.
    // tree max + defer-max (THR=8 log2); exp fused with bf16 pack into u[8];
    // then permlane32_swap + xor16 exchange -> pf (PV B-fragments, in-reg).
    bf16x8 pf[2][4];
    float alch[2];
    for (int qb = 0; qb < 2; qb++) {
      float mk[8];
#pragma unroll
      for (int kb = 0; kb < 8; kb++)
        mk[kb] = fmaxf(fmaxf(s[kb][qb][0], s[kb][qb][1]),
                       fmaxf(s[kb][qb][2], s[kb][qb][3]));
      float mx = fmaxf(fmaxf(fmaxf(mk[0], mk[1]), fmaxf(mk[2], mk[3])),
                       fmaxf(fmaxf(mk[4], mk[5]), fmaxf(mk[6], mk[7])));
      mx = fmaxf(mx, __shfl_xor(mx, 16, 64));
      mx = fmaxf(mx, __shfl_xor(mx, 32, 64));
      float mn = m_[qb], al = 1.0f;
      if (!__all(mx <= m_[qb] + 8.0f)) {
        mn = fmaxf(m_[qb], mx);
        al = exp2f(m_[qb] - mn);
        m_[qb] = mn;
      }
      alch[qb] = al;
      uint2 u[8];
      float rs = 0.f;
#pragma unroll
      for (int kb = 0; kb < 8; kb++) {
        float p0 = exp2f(s[kb][qb][0] - mn), p1 = exp2f(s[kb][qb][1] - mn);
        float p2 = exp2f(s[kb][qb][2] - mn), p3 = exp2f(s[kb][qb][3] - mn);
        u[kb] = pack4(p0, p1, p2, p3);
        rs += (p0 + p1) + (p2 + p3);
      }
      rs += __shfl_xor(rs, 16, 64);
      rs += __shfl_xor(rs, 32, 64);
      l_[qb] = l_[qb] * al + rs;
      // exchange: pf[qb][ki] = P[q=l16-row][keys ki*32 + quad*8 + 0..7].
      // permlane32_swap(a,b): a' = [a_lo, b_lo], b' = [a_hi, b_hi].
      const bool qo = (quad & 1) != 0;
#pragma unroll
      for (int ki = 0; ki < 4; ki++) {
        u32x2 r1 = __builtin_amdgcn_permlane32_swap(u[2 * ki].x, u[2 * ki + 1].x, false, false);
        u32x2 r2 = __builtin_amdgcn_permlane32_swap(u[2 * ki].y, u[2 * ki + 1].y, false, false);
        uint32_t t1b = (uint32_t)__shfl_xor((int)r1[1], 16, 64);
        uint32_t t1a = (uint32_t)__shfl_xor((int)r1[0], 16, 64);
        uint32_t t2b = (uint32_t)__shfl_xor((int)r2[1], 16, 64);
        uint32_t t2a = (uint32_t)__shfl_xor((int)r2[0], 16, 64);
        uint4 d;
        d.x = qo ? t1b : (uint32_t)r1[0];
        d.y = qo ? t2b : (uint32_t)r2[0];
        d.z = qo ? (uint32_t)r1[1] : t1a;
        d.w = qo ? (uint32_t)r2[1] : t2a;
        pf[qb][ki] = *(bf16x8*)&d;
      }
    }
    // O-rescale (only when some row deferred past THR)
    if (alch[0] != 1.0f || alch[1] != 1.0f) {
#pragma unroll
      for (int db = 0; db < 8; db++) {
        o[db][0] *= alch[0];
        o[db][1] *= alch[1];
      }
    }

    // BARRIER_B: drain V_kt (8 older loads; the 8 K_{kt+1} stay flying)
    if (kt == 15) asm volatile("s_waitcnt vmcnt(0)" ::: "memory");
    else          asm volatile("s_waitcnt vmcnt(8)" ::: "memory");
    bar_sync();

    // O^T += V^T P^T : A = V-frag (m=d), B = pf (n=q, in registers)
    for (int db = 0; db < 8; db++) {
      bf16x8 vf[4];
      int a0 = (db * 16 + l16) * 128 + ((quad ^ sw) << 3);
      for (int ki = 0; ki < 4; ki++)
        vf[ki] = *(const bf16x8*)&Vls[a0 ^ (ki * 32)];
      __builtin_amdgcn_s_setprio(1);
      for (int qb = 0; qb < 2; qb++)
        for (int ki = 0; ki < 4; ki++)
          o[db][qb] = __builtin_amdgcn_mfma_f32_16x16x32_bf16(vf[ki], pf[qb][ki], o[db][qb], 0, 0, 0);
      __builtin_amdgcn_s_setprio(0);
    }

    // BARRIER_END: K_{kt+1} landed (covered by softmax+PV); Vls free after
    asm volatile("s_waitcnt vmcnt(0)" ::: "memory");
    bar_sync();
  }

  // epilogue: O^T/l -> LDS [q][d] packed b64 -> coalesced global store
  float inv[2] = {1.0f / l_[0], 1.0f / l_[1]};
  for (int qb = 0; qb < 2; qb++) {
    int rq = wave * 32 + qb * 16 + l16;
    for (int db = 0; db < 8; db++) {
      int ch = (db * 2 + (quad >> 1)) ^ sw;
      uint2 pv = pack4(o[db][qb][0] * inv[qb], o[db][qb][1] * inv[qb],
                       o[db][qb][2] * inv[qb], o[db][qb][3] * inv[qb]);
      *(uint2*)&KP[rq * 128 + (ch << 3) + (quad & 1) * 4] = pv;
    }
  }
  __syncthreads();
  u16* Ab = AO + (size_t)(b * 2048 + qt * 128) * 2048 + h * 128;
  for (int i = 0; i < 8; i++) {
    int row = i * 16 + (tid >> 4);
    int seg = tid & 15;
    int pc = seg ^ (row & 7);
    *(uint4*)(Ab + (size_t)row * 2048 + seg * 8) = *(const uint4*)&KP[row * 128 + pc * 8];
  }
}

// ---------------- launch ----------------
extern "C" void kernel_launch(void* const* d_in, const int* in_sizes, int n_in,
                              void* d_out, int out_size, void* d_ws, size_t ws_size,
                              hipStream_t stream) {
  (void)in_sizes; (void)n_in; (void)out_size; (void)ws_size;
  const float* x    = (const float*)d_in[0];
  const float* fcos = (const float*)d_in[1];
  const float* fsin = (const float*)d_in[2];
  const float* wq   = (const float*)d_in[3];
  const float* wk   = (const float*)d_in[4];
  const float* wv   = (const float*)d_in[5];
  const float* wo   = (const float*)d_in[6];

  char* w = (char*)d_ws;
  u16* xb  = (u16*)w;                               // 8192x2048 bf16, reused as attn_out
  u16* wT  = (u16*)(w + 33554432);                  // 3072x2048 bf16
  u16* woT = (u16*)(w + 33554432 + 12582912);       // 2048x2048 bf16
  u16* QKV = (u16*)(w + 33554432 + 12582912 + 8388608);            // 8192x3072 bf16
  u16* Vt  = (u16*)(w + 33554432 + 12582912 + 8388608 + 50331648); // 16x128x2048 bf16
  u16* AO  = xb;

  const float C = 0.08838834764831845f * 1.44269504088896340f;  // 1/sqrt(128)*log2(e)

  cast_x_kernel<<<16384, 256, 0, stream>>>((const float4*)x, (ushort4*)xb);
  wtrans_kernel<<<dim3(64, 64), dim3(32, 8), 0, stream>>>(wq, wT, 2048, 2048, C);
  wtrans_kernel<<<dim3(16, 64), dim3(32, 8), 0, stream>>>(wk, wT + (size_t)2048 * 2048, 2048, 512, 1.0f);
  wtrans_kernel<<<dim3(16, 64), dim3(32, 8), 0, stream>>>(wv, wT + (size_t)2560 * 2048, 2048, 512, 1.0f);
  wtrans_kernel<<<dim3(64, 64), dim3(32, 8), 0, stream>>>(wo, woT, 2048, 2048, 1.0f);

  gemm_bt_kernel<true><<<dim3(24, 64), 256, 0, stream>>>(xb, wT, QKV, 2048, 3072);
  rope_kernel<<<40960, 256, 0, stream>>>(QKV, fcos, fsin);
  vtrans_kernel<<<dim3(64, 4, 16), dim3(32, 8), 0, stream>>>(QKV, Vt);
  attn_kernel<<<dim3(16, 16, 4), 256, 0, stream>>>(QKV, Vt, AO);
  gemm_bt_kernel<false><<<dim3(16, 64), 256, 0, stream>>>(AO, woT, (float*)d_out, 2048, 2048);
}